// Round 13
// baseline (802.668 us; speedup 1.0000x reference)
//
#include <hip/hip_runtime.h>

#define N_NODES  100000
#define N_EDGES  1600000
#define N_GRAPHS 128
#define SCAN_BLOCKS 98   // ceil(100000/1024)

typedef unsigned short u16;
typedef unsigned int   u32;
typedef __attribute__((ext_vector_type(8))) short short8;
typedef __attribute__((ext_vector_type(4))) float f32x4;

__device__ __forceinline__ float bf2f(u16 v) {
  union { u32 i; float f; } u; u.i = ((u32)v) << 16; return u.f;
}
__device__ __forceinline__ u16 f2bf(float f) {
  union { float f; u32 i; } u; u.f = f;
  u32 r = (u.i + 0x7fffu + ((u.i >> 16) & 1u)) >> 16;
  return (u16)r;
}
__device__ __forceinline__ float sigmoid_f(float x) { return 1.f / (1.f + __expf(-x)); }
__device__ __forceinline__ float tanh_f(float x) {
  x = fminf(15.f, fmaxf(-15.f, x));
  float e = __expf(2.f * x);
  return (e - 1.f) / (e + 1.f);
}
__device__ __forceinline__ int geti(const int* __restrict__ p, int i, int is64) {
  return p[is64 ? (2 * i) : i];
}

// Detect whether edge_index / batch are int64 (all sampled odd words == 0) or int32.
__global__ void detect_i64_kernel(const int* __restrict__ ei, const int* __restrict__ batch,
                                  int* __restrict__ flags) {
  int lane = threadIdx.x;  // 64
  {
    long long q = (long long)lane * (3200000 / 2 - 1) / 63;
    int pos = (int)(2 * q + 1);
    unsigned long long m = __ballot(ei[pos] != 0);
    if (lane == 0) flags[0] = (m == 0ull) ? 1 : 0;
  }
  {
    long long q = (long long)lane * (100000 / 2 - 1) / 63;
    int pos = (int)(2 * q + 1);
    unsigned long long m = __ballot(batch[pos] != 0);
    if (lane == 0) flags[1] = (m == 0ull) ? 1 : 0;
  }
}

// ---------------- CSR build ----------------
// XCD-localized histogram (round 12: removed 53 MB of cross-XCD atomic line ping-pong).
__global__ void hist_kernel(const int* __restrict__ ei, const int* __restrict__ flags,
                            int* __restrict__ counts8, u16* __restrict__ rankb) {
  int e = blockIdx.x * 256 + threadIdx.x;
  if (e < N_EDGES) {
    int f = flags[0];
    int d = geti(ei, N_EDGES + e, f);
    int g = blockIdx.x & 7;
    int r = atomicAdd(&counts8[g * N_NODES + d], 1);
    rankb[e] = (u16)(r | (g << 12));   // per-(g,d) rank < 4096
  }
}

// counts[d] = sum_g counts8[g][d]; px[g][d] = prefix over groups.
__global__ void sum8_kernel(const int* __restrict__ counts8, int* __restrict__ counts,
                            int* __restrict__ px) {
  int d = blockIdx.x * 256 + threadIdx.x;
  if (d < N_NODES) {
    int run = 0;
#pragma unroll
    for (int x = 0; x < 8; ++x) {
      px[x * N_NODES + d] = run;
      run += counts8[x * N_NODES + d];
    }
    counts[d] = run;
  }
}

__global__ __launch_bounds__(1024)
void scanA_kernel(const int* __restrict__ counts, int* __restrict__ blocksums) {
  __shared__ int red[16];
  int i = blockIdx.x * 1024 + threadIdx.x;
  int v = (i < N_NODES) ? counts[i] : 0;
  for (int o = 32; o > 0; o >>= 1) v += __shfl_down(v, o, 64);
  int wv = threadIdx.x >> 6, lane = threadIdx.x & 63;
  if (lane == 0) red[wv] = v;
  __syncthreads();
  if (threadIdx.x < 16) {
    int s = red[threadIdx.x];
    for (int o = 8; o > 0; o >>= 1) s += __shfl_down(s, o, 64);
    if (threadIdx.x == 0) blocksums[blockIdx.x] = s;
  }
}

__global__ void scanB_kernel(const int* __restrict__ blocksums, int* __restrict__ blockbase,
                             int* __restrict__ offsets) {
  if (threadIdx.x == 0) {
    int run = 0;
    for (int b = 0; b < SCAN_BLOCKS; ++b) { blockbase[b] = run; run += blocksums[b]; }
    offsets[N_NODES] = run;
  }
}

__global__ __launch_bounds__(1024)
void scanC_kernel(const int* __restrict__ counts, const int* __restrict__ blockbase,
                  int* __restrict__ offsets) {
  __shared__ int buf[1024];
  int t = threadIdx.x;
  int i = blockIdx.x * 1024 + t;
  int v = (i < N_NODES) ? counts[i] : 0;
  buf[t] = v;
  __syncthreads();
  for (int o = 1; o < 1024; o <<= 1) {
    int add = (t >= o) ? buf[t - o] : 0;
    __syncthreads();
    buf[t] += add;
    __syncthreads();
  }
  if (i < N_NODES) offsets[i] = buf[t] - v + blockbase[blockIdx.x];
}

// base8[g][d] = offsets[d] + px[g][d]  -> scatter does ONE random read per edge
// (round 12 regression: offs[d] + px[g][d] separately doubled random reads).
__global__ void base8_kernel(const int* __restrict__ offsets, const int* __restrict__ px,
                             int* __restrict__ base8) {
  int i = blockIdx.x * 256 + threadIdx.x;
  if (i < 8 * N_NODES) base8[i] = offsets[i % N_NODES] + px[i];
}

__global__ void scatter_kernel(const int* __restrict__ ei, const int* __restrict__ flags,
                               const int* __restrict__ base8, const u16* __restrict__ rankb,
                               int* __restrict__ ssrc) {
  int e = blockIdx.x * 256 + threadIdx.x;
  if (e < N_EDGES) {
    int f = flags[0];
    int d = geti(ei, N_EDGES + e, f);
    int pr = (int)rankb[e];
    int g = pr >> 12, r = pr & 0xfff;
    ssrc[base8[g * N_NODES + d] + r] = geti(ei, e, f);
  }
}

// ---------------- weight prep ----------------
// f32 [K][N] row-major -> bf16 [N][K]
__global__ void transpose_kernel(const float* __restrict__ in, u16* __restrict__ out, int K, int N) {
  int i = blockIdx.x * 256 + threadIdx.x;
  if (i < K * N) {
    int k = i / N, n = i % N;
    out[n * K + k] = f2bf(in[i]);
  }
}

// W'_l[k][c] = sum_j ggnn_w[l][k][j] * w_ih[j][c]   (f32, [3][128][384])
__global__ void wprime_kernel(const float* __restrict__ ggnn_w, const float* __restrict__ w_ih,
                              float* __restrict__ wp) {
  int i = blockIdx.x * 256 + threadIdx.x;
  if (i >= 3 * 128 * 384) return;
  int l = i / (128 * 384), r = i % (128 * 384), k = r / 384, c = r % 384;
  const float* W = ggnn_w + l * 128 * 128;
  float s = 0.f;
  for (int j = 0; j < 128; ++j) s += W[k * 128 + j] * w_ih[j * 384 + c];
  wp[i] = s;
}

// Packed GRU weight: b2p[ci][idx][e] u16, ci=0..7 (k-chunk), idx = ko*384 + n_lin,
// e=0..7. Zero quadrants excluded (ci<4: W' cols r|z|in; ci>=4: w_hh cols r|z|hn).
__global__ void build_b2p_kernel(const float* __restrict__ wp, const float* __restrict__ w_hh,
                                 u16* __restrict__ b2p) {
  int g = blockIdx.x * 256 + threadIdx.x;
  if (g >= 8 * 1536 * 8) return;
  int e = g & 7;
  int grp = g >> 3;
  int ci = grp / 1536;
  int idx = grp % 1536;
  int n_lin = idx % 384;
  int ko = idx / 384;
  int k = ci * 32 + ko * 8 + e;
  float v = (k < 128) ? wp[k * 384 + n_lin] : w_hh[(k - 128) * 384 + n_lin];
  b2p[g] = f2bf(v);
}

// ---------------- node projection GEMM (f32 A -> bf16 frags) ----------------
__global__ __launch_bounds__(256)
void nodeproj_gemm(const float* __restrict__ A, const u16* __restrict__ BT,
                   const float* __restrict__ bias, u16* __restrict__ out, int M)
{
  constexpr int K_DIM = 64, N_DIM = 128, NT = 8, NCHUNK = 2;
  __shared__ u16 B_lds[N_DIM * 40];
  const int tid = threadIdx.x, lane = tid & 63, w = tid >> 6;
  const int strip = blockIdx.x * 64;
  const int ksub = (lane >> 4) * 8;
  union Frag { uint4 u; short8 s; };
  Frag af[NCHUNK];
  const int m_node = strip + w * 16 + (lane & 15);
  const bool avalid = (m_node < M);
#pragma unroll
  for (int ci = 0; ci < NCHUNK; ++ci) {
    int k0 = ci * 32 + ksub;
    short8 sv = {0,0,0,0,0,0,0,0};
    if (avalid) {
      const float* p = A + (size_t)m_node * K_DIM + k0;
      float4 f0 = *(const float4*)p;
      float4 f1 = *(const float4*)(p + 4);
      sv[0]=(short)f2bf(f0.x); sv[1]=(short)f2bf(f0.y); sv[2]=(short)f2bf(f0.z); sv[3]=(short)f2bf(f0.w);
      sv[4]=(short)f2bf(f1.x); sv[5]=(short)f2bf(f1.y); sv[6]=(short)f2bf(f1.z); sv[7]=(short)f2bf(f1.w);
    }
    af[ci].s = sv;
  }
  f32x4 acc[NT];
#pragma unroll
  for (int t = 0; t < NT; ++t) acc[t] = {0.f, 0.f, 0.f, 0.f};
  const int boff = (lane & 15) * 40 + ksub;
#pragma unroll
  for (int ci = 0; ci < NCHUNK; ++ci) {
    if (ci) __syncthreads();
    for (int g = tid; g < N_DIM * 4; g += 256) {
      int n = g >> 2, ko = g & 3;
      uint4 bv = *(const uint4*)(BT + (size_t)n * K_DIM + ci * 32 + ko * 8);
      *(uint4*)(&B_lds[n * 40 + ko * 8]) = bv;
    }
    __syncthreads();
    short8 a = af[ci].s;
#pragma unroll
    for (int t = 0; t < NT; ++t) {
      const short8 b = *(const short8*)(&B_lds[t * 16 * 40 + boff]);
      acc[t] = __builtin_amdgcn_mfma_f32_16x16x32_bf16(a, b, acc[t], 0, 0, 0);
    }
  }
  const int mrow = (lane >> 4) * 4;
#pragma unroll
  for (int t = 0; t < NT; ++t) {
    int col = t * 16 + (lane & 15);
    float bv = bias[col];
#pragma unroll
    for (int r = 0; r < 4; ++r) {
      int node = strip + w * 16 + mrow + r;
      if (node < M) out[(size_t)node * N_DIM + col] = f2bf(fmaxf(acc[t][r] + bv, 0.f));
    }
  }
}

// ---------------- FUSED layer: CSR gather (->LDS) + GRU GEMM + epilogue ----------------
// Block = 256 thr / 32-row strip (100000 % 32 == 0 -> no bounds checks).
// Phase 1: each wave gathers 8 nodes' edge-sums into A_lds[32][136] bf16 (pad 8 -> 2-way banks).
// Phase 2 (after ONE barrier): round-11 pipelined MFMA loop; chunks 0-3 read A from LDS,
// chunks 4-7 stream h from global (ping-pong prefetch with B).
// Eliminates the 25 MB aggb write + 25 MB re-read per layer and one dispatch.
__global__ __launch_bounds__(256)
void fused_layer(const u16* __restrict__ h, const int* __restrict__ ssrc,
                 const int* __restrict__ offsets, const u16* __restrict__ b2p,
                 const float* __restrict__ b_ih, const float* __restrict__ b_hh,
                 u16* __restrict__ hout)
{
  __shared__ u16 A_lds[32 * 136];   // 8.5 KB
  const int tid  = threadIdx.x;
  const int lane = tid & 63;
  const int w    = tid >> 6;        // wave 0..3 (= col-quarter in phase 2)
  const int strip = blockIdx.x * 32;
  const int lrow  = lane & 15;
  const int quad  = lane >> 4;
  const int ksub  = quad * 8;

  // ---- Phase 1: gather agg rows for nodes strip+w*8 .. +8 ----
  {
    const int g = quad, l = lrow;   // g: edge group, l: 16B column index
    for (int ni = 0; ni < 8; ++ni) {
      const int node = strip + w * 8 + ni;
      int beg = offsets[node], end = offsets[node + 1];
      float s[8] = {0.f,0.f,0.f,0.f,0.f,0.f,0.f,0.f};
      for (int e = beg; e < end; e += 8) {
        uint4 v0 = {0u,0u,0u,0u}, v1 = {0u,0u,0u,0u};
        int e0 = e + g, e1 = e + 4 + g;
        if (e0 < end) { int src = ssrc[e0]; v0 = *(const uint4*)(h + (size_t)src * 128 + l * 8); }
        if (e1 < end) { int src = ssrc[e1]; v1 = *(const uint4*)(h + (size_t)src * 128 + l * 8); }
        u32 w0[4] = {v0.x, v0.y, v0.z, v0.w};
        u32 w1[4] = {v1.x, v1.y, v1.z, v1.w};
#pragma unroll
        for (int i = 0; i < 4; ++i) {
          s[2*i]   += bf2f((u16)(w0[i] & 0xffffu)) + bf2f((u16)(w1[i] & 0xffffu));
          s[2*i+1] += bf2f((u16)(w0[i] >> 16))     + bf2f((u16)(w1[i] >> 16));
        }
      }
#pragma unroll
      for (int i = 0; i < 8; ++i) {
        s[i] += __shfl_xor(s[i], 16, 64);
        s[i] += __shfl_xor(s[i], 32, 64);
      }
      if (g == 0) {
        uint4 o;
        o.x = (u32)f2bf(s[0]) | ((u32)f2bf(s[1]) << 16);
        o.y = (u32)f2bf(s[2]) | ((u32)f2bf(s[3]) << 16);
        o.z = (u32)f2bf(s[4]) | ((u32)f2bf(s[5]) << 16);
        o.w = (u32)f2bf(s[6]) | ((u32)f2bf(s[7]) << 16);
        *(uint4*)(&A_lds[(w * 8 + ni) * 136 + l * 8]) = o;
      }
    }
  }
  __syncthreads();

  // ---- Phase 2: GEMM + GRU epilogue (wave w = col-quarter qc) ----
  const int qc = w;
  f32x4 ar[2][2], az[2][2], ain[2][2], ahn[2][2];
#pragma unroll
  for (int s = 0; s < 2; ++s)
#pragma unroll
    for (int t = 0; t < 2; ++t) {
      ar[s][t] = {0.f,0.f,0.f,0.f}; az[s][t] = {0.f,0.f,0.f,0.f};
      ain[s][t] = {0.f,0.f,0.f,0.f}; ahn[s][t] = {0.f,0.f,0.f,0.f};
    }

  union Frag { uint4 u; short8 s8; };
  const int node0 = strip + lrow;
  const int node1 = strip + 16 + lrow;
  const u16* bb = b2p + ((size_t)quad * 384 + qc * 32 + lrow) * 8;

  Frag ha0[2], ha1[2], fbr[2][2], fbz[2][2], fbg[2][2];

  auto ldB = [&](int ci, int p) {
    const u16* cb = bb + ci * 12288;
    fbr[p][0].u = *(const uint4*)(cb);
    fbr[p][1].u = *(const uint4*)(cb + 128);
    fbz[p][0].u = *(const uint4*)(cb + 1024);
    fbz[p][1].u = *(const uint4*)(cb + 1024 + 128);
    fbg[p][0].u = *(const uint4*)(cb + 2048);
    fbg[p][1].u = *(const uint4*)(cb + 2048 + 128);
  };
  auto ldH = [&](int ci, int p) {
    const u16* ap = h + (ci - 4) * 32 + ksub;
    ha0[p].u = *(const uint4*)(ap + (size_t)node0 * 128);
    ha1[p].u = *(const uint4*)(ap + (size_t)node1 * 128);
  };

  ldB(0, 0);
#pragma unroll
  for (int ci = 0; ci < 8; ++ci) {
    const int p = ci & 1, q = p ^ 1;
    if (ci < 7) { ldB(ci + 1, q); if (ci + 1 >= 4) ldH(ci + 1, q); }
    Frag a0, a1;
    if (ci < 4) {  // A from LDS (agg), 2-way banks
      a0.u = *(const uint4*)(&A_lds[lrow * 136 + ci * 32 + ksub]);
      a1.u = *(const uint4*)(&A_lds[(lrow + 16) * 136 + ci * 32 + ksub]);
    } else {
      a0 = ha0[p]; a1 = ha1[p];
    }
#pragma unroll
    for (int t = 0; t < 2; ++t) {
      ar[0][t] = __builtin_amdgcn_mfma_f32_16x16x32_bf16(a0.s8, fbr[p][t].s8, ar[0][t], 0, 0, 0);
      ar[1][t] = __builtin_amdgcn_mfma_f32_16x16x32_bf16(a1.s8, fbr[p][t].s8, ar[1][t], 0, 0, 0);
      az[0][t] = __builtin_amdgcn_mfma_f32_16x16x32_bf16(a0.s8, fbz[p][t].s8, az[0][t], 0, 0, 0);
      az[1][t] = __builtin_amdgcn_mfma_f32_16x16x32_bf16(a1.s8, fbz[p][t].s8, az[1][t], 0, 0, 0);
    }
    if (ci < 4) {
#pragma unroll
      for (int t = 0; t < 2; ++t) {
        ain[0][t] = __builtin_amdgcn_mfma_f32_16x16x32_bf16(a0.s8, fbg[p][t].s8, ain[0][t], 0, 0, 0);
        ain[1][t] = __builtin_amdgcn_mfma_f32_16x16x32_bf16(a1.s8, fbg[p][t].s8, ain[1][t], 0, 0, 0);
      }
    } else {
#pragma unroll
      for (int t = 0; t < 2; ++t) {
        ahn[0][t] = __builtin_amdgcn_mfma_f32_16x16x32_bf16(a0.s8, fbg[p][t].s8, ahn[0][t], 0, 0, 0);
        ahn[1][t] = __builtin_amdgcn_mfma_f32_16x16x32_bf16(a1.s8, fbg[p][t].s8, ahn[1][t], 0, 0, 0);
      }
    }
  }

  // GRU epilogue. D layout per tile: row = quad*4 + r, col = lrow.
#pragma unroll
  for (int t = 0; t < 2; ++t) {
    const int c = qc * 32 + t * 16 + lrow;
    const float brr = b_ih[c] + b_hh[c];
    const float bzz = b_ih[128 + c] + b_hh[128 + c];
    const float bin = b_ih[256 + c];
    const float bhn = b_hh[256 + c];
#pragma unroll
    for (int s = 0; s < 2; ++s) {
#pragma unroll
      for (int r = 0; r < 4; ++r) {
        const int nrow = strip + s * 16 + quad * 4 + r;
        float rg = sigmoid_f(ar[s][t][r] + brr);
        float zg = sigmoid_f(az[s][t][r] + bzz);
        float hv = ahn[s][t][r] + bhn;
        float ng = tanh_f(ain[s][t][r] + bin + rg * hv);
        float hp = bf2f(h[(size_t)nrow * 128 + c]);
        hout[(size_t)nrow * 128 + c] = f2bf((1.f - zg) * ng + zg * hp);
      }
    }
  }
}

// ---------------- parallel segmented mean-pool (batch is sorted) ----------------
__global__ __launch_bounds__(256)
void pool_kernel(const u16* __restrict__ h, const int* __restrict__ batch,
                 const int* __restrict__ flags, float* __restrict__ sums)
{
  const int c = threadIdx.x & 127;
  const int half = threadIdx.x >> 7;
  const int base = blockIdx.x * 128;
  const int f = flags[1];
  int gcur = -1; float s = 0.f;
  for (int i = half; i < 128; i += 2) {
    int n = base + i;
    if (n >= N_NODES) break;
    int g = geti(batch, n, f);
    if (g != gcur) {
      if (gcur >= 0) atomicAdd(&sums[gcur * 128 + c], s);
      s = 0.f; gcur = g;
    }
    s += bf2f(h[(size_t)n * 128 + c]);
  }
  if (gcur >= 0) atomicAdd(&sums[gcur * 128 + c], s);
}

// ---------------- doc proj + LN + fusion + heads, f32 (one block per graph) ----------------
__global__ __launch_bounds__(256)
void head2_kernel(const float* __restrict__ sums, const int* __restrict__ batch,
                  const int* __restrict__ flags,
                  const float* __restrict__ doc, const float* __restrict__ doc_w, const float* __restrict__ doc_b,
                  const float* __restrict__ ln_g, const float* __restrict__ ln_b,
                  const float* __restrict__ fus_w, const float* __restrict__ fus_b,
                  const float* __restrict__ task_w, const float* __restrict__ task_b,
                  const float* __restrict__ time_w, const float* __restrict__ time_b,
                  float* __restrict__ out_task, float* __restrict__ out_time)
{
  const int g = blockIdx.x;
  const int t = threadIdx.x;
  __shared__ float fusion[256];
  __shared__ float fh[128];
  __shared__ float dpart[256];
  __shared__ int seg[2];

  if (t < 2) {
    int f = flags[1];
    int target = g + t, lo = 0, hi = N_NODES;
    while (lo < hi) { int mid = (lo + hi) >> 1; if (geti(batch, mid, f) < target) lo = mid + 1; else hi = mid; }
    seg[t] = lo;
  }
  {
    int c = t & 127, kh = t >> 7;
    float s = 0.f;
    for (int k = kh * 384; k < kh * 384 + 384; ++k) s += doc[g * 768 + k] * doc_w[k * 128 + c];
    dpart[t] = s;
  }
  __syncthreads();

  if (t < 128) {
    float cnt = (float)(seg[1] - seg[0]);
    fusion[t] = sums[g * 128 + t] / fmaxf(cnt, 1.f);
  } else {
    int c = t - 128;
    fusion[t] = fmaxf(dpart[c] + dpart[c + 128] + doc_b[c], 0.f);
  }
  __syncthreads();

  float mu = 0.f;
  for (int i = 0; i < 256; ++i) mu += fusion[i];
  mu *= (1.f / 256.f);
  float var = 0.f;
  for (int i = 0; i < 256; ++i) { float d = fusion[i] - mu; var += d * d; }
  var *= (1.f / 256.f);
  float inv = rsqrtf(var + 1e-5f);
  float norm = (fusion[t] - mu) * inv * ln_g[t] + ln_b[t];
  __syncthreads();
  fusion[t] = norm;
  __syncthreads();

  if (t < 128) {
    float s = 0.f;
    for (int k = 0; k < 256; ++k) s += fusion[k] * fus_w[k * 128 + t];
    s += fus_b[t];
    fh[t] = fmaxf(s, 0.f);
  }
  __syncthreads();

  if (t < 32) {
    float s = 0.f;
    for (int k = 0; k < 128; ++k) s += fh[k] * task_w[k * 32 + t];
    s += task_b[t];
    out_task[g * 32 + t] = s;
  }
  if (t == 32) {
    float s = 0.f;
    for (int k = 0; k < 128; ++k) s += fh[k] * time_w[k];
    s += time_b[0];
    out_time[g] = s;
  }
}

// ---------------- launch ----------------
extern "C" void kernel_launch(void* const* d_in, const int* in_sizes, int n_in,
                              void* d_out, int out_size, void* d_ws, size_t ws_size,
                              hipStream_t stream)
{
  const float* x        = (const float*)d_in[0];
  const float* doc      = (const float*)d_in[1];
  const int*   ei       = (const int*)d_in[2];
  const int*   batch    = (const int*)d_in[3];
  const float* node_w   = (const float*)d_in[4];
  const float* node_b   = (const float*)d_in[5];
  const float* ggnn_w   = (const float*)d_in[6];
  const float* gru_w_ih = (const float*)d_in[7];
  const float* gru_b_ih = (const float*)d_in[8];
  const float* gru_w_hh = (const float*)d_in[9];
  const float* gru_b_hh = (const float*)d_in[10];
  const float* doc_w    = (const float*)d_in[11];
  const float* doc_b    = (const float*)d_in[12];
  const float* ln_g     = (const float*)d_in[13];
  const float* ln_b     = (const float*)d_in[14];
  const float* fus_w    = (const float*)d_in[15];
  const float* fus_b    = (const float*)d_in[16];
  const float* task_w   = (const float*)d_in[17];
  const float* task_b   = (const float*)d_in[18];
  const float* time_w   = (const float*)d_in[19];
  const float* time_b   = (const float*)d_in[20];

  char* ws = (char*)d_ws;
  size_t off = 0;
  auto alloc = [&](size_t bytes) -> void* {
    void* p = ws + off;
    off = (off + bytes + 255) & ~(size_t)255;
    return p;
  };
  u16* hA      = (u16*)alloc((size_t)N_NODES * 128 * 2);
  u16* hB      = (u16*)alloc((size_t)N_NODES * 128 * 2);
  u16* nwT     = (u16*)alloc(64 * 128 * 2);
  u16* b2p     = (u16*)alloc(3 * 8 * 1536 * 8 * 2);
  float* wp    = (float*)alloc(3 * 128 * 384 * 4);
  float* sums  = (float*)alloc(N_GRAPHS * 128 * 4);
  int* counts8 = (int*)alloc((size_t)8 * N_NODES * 4);
  int* px      = (int*)alloc((size_t)8 * N_NODES * 4);
  int* base8   = (int*)alloc((size_t)8 * N_NODES * 4);
  int* counts  = (int*)alloc((size_t)N_NODES * 4);
  int* offs    = (int*)alloc((size_t)(N_NODES + 1) * 4);
  int* ssrc    = (int*)alloc((size_t)N_EDGES * 4);
  u16* rankb   = (u16*)alloc((size_t)N_EDGES * 2);
  int* bsum    = (int*)alloc(SCAN_BLOCKS * 4);
  int* bbase   = (int*)alloc(SCAN_BLOCKS * 4);
  int* flags   = (int*)alloc(2 * 4);

  hipMemsetAsync(counts8, 0, (size_t)8 * N_NODES * 4, stream);
  hipMemsetAsync(sums, 0, (size_t)N_GRAPHS * 128 * 4, stream);

  detect_i64_kernel<<<1, 64, 0, stream>>>(ei, batch, flags);
  hist_kernel<<<(N_EDGES + 255) / 256, 256, 0, stream>>>(ei, flags, counts8, rankb);
  sum8_kernel<<<(N_NODES + 255) / 256, 256, 0, stream>>>(counts8, counts, px);
  scanA_kernel<<<SCAN_BLOCKS, 1024, 0, stream>>>(counts, bsum);
  scanB_kernel<<<1, 64, 0, stream>>>(bsum, bbase, offs);
  scanC_kernel<<<SCAN_BLOCKS, 1024, 0, stream>>>(counts, bbase, offs);
  base8_kernel<<<(8 * N_NODES + 255) / 256, 256, 0, stream>>>(offs, px, base8);
  scatter_kernel<<<(N_EDGES + 255) / 256, 256, 0, stream>>>(ei, flags, base8, rankb, ssrc);

  transpose_kernel<<<(64 * 128 + 255) / 256, 256, 0, stream>>>(node_w, nwT, 64, 128);
  wprime_kernel<<<(3 * 128 * 384 + 255) / 256, 256, 0, stream>>>(ggnn_w, gru_w_ih, wp);
  for (int l = 0; l < 3; ++l)
    build_b2p_kernel<<<(8 * 1536 * 8 + 255) / 256, 256, 0, stream>>>(
        wp + l * 128 * 384, gru_w_hh, b2p + (size_t)l * 8 * 1536 * 8);

  const int GB = (N_NODES + 63) / 64;    // 1563
  const int GB32 = N_NODES / 32;         // 3125
  nodeproj_gemm<<<GB, 256, 0, stream>>>(x, nwT, node_b, hA, N_NODES);

  u16* hcur = hA;
  u16* hnext = hB;
  for (int l = 0; l < 3; ++l) {
    fused_layer<<<GB32, 256, 0, stream>>>(hcur, ssrc, offs, b2p + (size_t)l * 8 * 1536 * 8,
                                          gru_b_ih, gru_b_hh, hnext);
    u16* tmp = hcur; hcur = hnext; hnext = tmp;
  }

  pool_kernel<<<(N_NODES + 127) / 128, 256, 0, stream>>>(hcur, batch, flags, sums);

  float* out_task = (float*)d_out;
  float* out_time = out_task + N_GRAPHS * 32;
  head2_kernel<<<N_GRAPHS, 256, 0, stream>>>(sums, batch, flags, doc, doc_w, doc_b, ln_g, ln_b,
                                             fus_w, fus_b, task_w, task_b, time_w, time_b,
                                             out_task, out_time);
}

// Round 14
// 680.529 us; speedup vs baseline: 1.1795x; 1.1795x over previous
//
#include <hip/hip_runtime.h>

#define N_NODES  100000
#define N_EDGES  1600000
#define N_GRAPHS 128
#define SCAN_BLOCKS 98   // ceil(100000/1024)

typedef unsigned short u16;
typedef unsigned int   u32;
typedef __attribute__((ext_vector_type(8))) short short8;
typedef __attribute__((ext_vector_type(4))) float f32x4;

__device__ __forceinline__ float bf2f(u16 v) {
  union { u32 i; float f; } u; u.i = ((u32)v) << 16; return u.f;
}
__device__ __forceinline__ u16 f2bf(float f) {
  union { float f; u32 i; } u; u.f = f;
  u32 r = (u.i + 0x7fffu + ((u.i >> 16) & 1u)) >> 16;
  return (u16)r;
}
__device__ __forceinline__ float sigmoid_f(float x) { return 1.f / (1.f + __expf(-x)); }
__device__ __forceinline__ float tanh_f(float x) {
  x = fminf(15.f, fmaxf(-15.f, x));
  float e = __expf(2.f * x);
  return (e - 1.f) / (e + 1.f);
}
__device__ __forceinline__ int geti(const int* __restrict__ p, int i, int is64) {
  return p[is64 ? (2 * i) : i];
}

// Detect whether edge_index / batch are int64 (all sampled odd words == 0) or int32.
__global__ void detect_i64_kernel(const int* __restrict__ ei, const int* __restrict__ batch,
                                  int* __restrict__ flags) {
  int lane = threadIdx.x;  // 64
  {
    long long q = (long long)lane * (3200000 / 2 - 1) / 63;
    int pos = (int)(2 * q + 1);
    unsigned long long m = __ballot(ei[pos] != 0);
    if (lane == 0) flags[0] = (m == 0ull) ? 1 : 0;
  }
  {
    long long q = (long long)lane * (100000 / 2 - 1) / 63;
    int pos = (int)(2 * q + 1);
    unsigned long long m = __ballot(batch[pos] != 0);
    if (lane == 0) flags[1] = (m == 0ull) ? 1 : 0;
  }
}

// ---------------- CSR build ----------------
// XCD-localized histogram (round 12: removed 53 MB of cross-XCD atomic line ping-pong).
__global__ void hist_kernel(const int* __restrict__ ei, const int* __restrict__ flags,
                            int* __restrict__ counts8, u16* __restrict__ rankb) {
  int e = blockIdx.x * 256 + threadIdx.x;
  if (e < N_EDGES) {
    int f = flags[0];
    int d = geti(ei, N_EDGES + e, f);
    int g = blockIdx.x & 7;
    int r = atomicAdd(&counts8[g * N_NODES + d], 1);
    rankb[e] = (u16)(r | (g << 12));   // per-(g,d) rank < 4096
  }
}

// counts[d] = sum_g counts8[g][d]; px[g][d] = prefix over groups.
__global__ void sum8_kernel(const int* __restrict__ counts8, int* __restrict__ counts,
                            int* __restrict__ px) {
  int d = blockIdx.x * 256 + threadIdx.x;
  if (d < N_NODES) {
    int run = 0;
#pragma unroll
    for (int x = 0; x < 8; ++x) {
      px[x * N_NODES + d] = run;
      run += counts8[x * N_NODES + d];
    }
    counts[d] = run;
  }
}

__global__ __launch_bounds__(1024)
void scanA_kernel(const int* __restrict__ counts, int* __restrict__ blocksums) {
  __shared__ int red[16];
  int i = blockIdx.x * 1024 + threadIdx.x;
  int v = (i < N_NODES) ? counts[i] : 0;
  for (int o = 32; o > 0; o >>= 1) v += __shfl_down(v, o, 64);
  int wv = threadIdx.x >> 6, lane = threadIdx.x & 63;
  if (lane == 0) red[wv] = v;
  __syncthreads();
  if (threadIdx.x < 16) {
    int s = red[threadIdx.x];
    for (int o = 8; o > 0; o >>= 1) s += __shfl_down(s, o, 64);
    if (threadIdx.x == 0) blocksums[blockIdx.x] = s;
  }
}

__global__ void scanB_kernel(const int* __restrict__ blocksums, int* __restrict__ blockbase,
                             int* __restrict__ offsets) {
  if (threadIdx.x == 0) {
    int run = 0;
    for (int b = 0; b < SCAN_BLOCKS; ++b) { blockbase[b] = run; run += blocksums[b]; }
    offsets[N_NODES] = run;
  }
}

__global__ __launch_bounds__(1024)
void scanC_kernel(const int* __restrict__ counts, const int* __restrict__ blockbase,
                  int* __restrict__ offsets) {
  __shared__ int buf[1024];
  int t = threadIdx.x;
  int i = blockIdx.x * 1024 + t;
  int v = (i < N_NODES) ? counts[i] : 0;
  buf[t] = v;
  __syncthreads();
  for (int o = 1; o < 1024; o <<= 1) {
    int add = (t >= o) ? buf[t - o] : 0;
    __syncthreads();
    buf[t] += add;
    __syncthreads();
  }
  if (i < N_NODES) offsets[i] = buf[t] - v + blockbase[blockIdx.x];
}

// base8[g][d] = offsets[d] + px[g][d]  -> scatter does ONE random read per edge.
__global__ void base8_kernel(const int* __restrict__ offsets, const int* __restrict__ px,
                             int* __restrict__ base8) {
  int i = blockIdx.x * 256 + threadIdx.x;
  if (i < 8 * N_NODES) base8[i] = offsets[i % N_NODES] + px[i];
}

__global__ void scatter_kernel(const int* __restrict__ ei, const int* __restrict__ flags,
                               const int* __restrict__ base8, const u16* __restrict__ rankb,
                               int* __restrict__ ssrc) {
  int e = blockIdx.x * 256 + threadIdx.x;
  if (e < N_EDGES) {
    int f = flags[0];
    int d = geti(ei, N_EDGES + e, f);
    int pr = (int)rankb[e];
    int g = pr >> 12, r = pr & 0xfff;
    ssrc[base8[g * N_NODES + d] + r] = geti(ei, e, f);
  }
}

// ---------------- weight prep ----------------
// f32 [K][N] row-major -> bf16 [N][K]
__global__ void transpose_kernel(const float* __restrict__ in, u16* __restrict__ out, int K, int N) {
  int i = blockIdx.x * 256 + threadIdx.x;
  if (i < K * N) {
    int k = i / N, n = i % N;
    out[n * K + k] = f2bf(in[i]);
  }
}

// W'_l[k][c] = sum_j ggnn_w[l][k][j] * w_ih[j][c]   (f32, [3][128][384])
__global__ void wprime_kernel(const float* __restrict__ ggnn_w, const float* __restrict__ w_ih,
                              float* __restrict__ wp) {
  int i = blockIdx.x * 256 + threadIdx.x;
  if (i >= 3 * 128 * 384) return;
  int l = i / (128 * 384), r = i % (128 * 384), k = r / 384, c = r % 384;
  const float* W = ggnn_w + l * 128 * 128;
  float s = 0.f;
  for (int j = 0; j < 128; ++j) s += W[k * 128 + j] * w_ih[j * 384 + c];
  wp[i] = s;
}

// Packed GRU weight: b2p[ci][idx][e] u16, ci=0..7 (k-chunk), idx = ko*384 + n_lin,
// e=0..7. Zero quadrants excluded (ci<4: W' cols r|z|in; ci>=4: w_hh cols r|z|hn).
__global__ void build_b2p_kernel(const float* __restrict__ wp, const float* __restrict__ w_hh,
                                 u16* __restrict__ b2p) {
  int g = blockIdx.x * 256 + threadIdx.x;
  if (g >= 8 * 1536 * 8) return;
  int e = g & 7;
  int grp = g >> 3;
  int ci = grp / 1536;
  int idx = grp % 1536;
  int n_lin = idx % 384;
  int ko = idx / 384;
  int k = ci * 32 + ko * 8 + e;
  float v = (k < 128) ? wp[k * 384 + n_lin] : w_hh[(k - 128) * 384 + n_lin];
  b2p[g] = f2bf(v);
}

// ---------------- node projection GEMM (f32 A -> bf16 frags) ----------------
__global__ __launch_bounds__(256)
void nodeproj_gemm(const float* __restrict__ A, const u16* __restrict__ BT,
                   const float* __restrict__ bias, u16* __restrict__ out, int M)
{
  constexpr int K_DIM = 64, N_DIM = 128, NT = 8, NCHUNK = 2;
  __shared__ u16 B_lds[N_DIM * 40];
  const int tid = threadIdx.x, lane = tid & 63, w = tid >> 6;
  const int strip = blockIdx.x * 64;
  const int ksub = (lane >> 4) * 8;
  union Frag { uint4 u; short8 s; };
  Frag af[NCHUNK];
  const int m_node = strip + w * 16 + (lane & 15);
  const bool avalid = (m_node < M);
#pragma unroll
  for (int ci = 0; ci < NCHUNK; ++ci) {
    int k0 = ci * 32 + ksub;
    short8 sv = {0,0,0,0,0,0,0,0};
    if (avalid) {
      const float* p = A + (size_t)m_node * K_DIM + k0;
      float4 f0 = *(const float4*)p;
      float4 f1 = *(const float4*)(p + 4);
      sv[0]=(short)f2bf(f0.x); sv[1]=(short)f2bf(f0.y); sv[2]=(short)f2bf(f0.z); sv[3]=(short)f2bf(f0.w);
      sv[4]=(short)f2bf(f1.x); sv[5]=(short)f2bf(f1.y); sv[6]=(short)f2bf(f1.z); sv[7]=(short)f2bf(f1.w);
    }
    af[ci].s = sv;
  }
  f32x4 acc[NT];
#pragma unroll
  for (int t = 0; t < NT; ++t) acc[t] = {0.f, 0.f, 0.f, 0.f};
  const int boff = (lane & 15) * 40 + ksub;
#pragma unroll
  for (int ci = 0; ci < NCHUNK; ++ci) {
    if (ci) __syncthreads();
    for (int g = tid; g < N_DIM * 4; g += 256) {
      int n = g >> 2, ko = g & 3;
      uint4 bv = *(const uint4*)(BT + (size_t)n * K_DIM + ci * 32 + ko * 8);
      *(uint4*)(&B_lds[n * 40 + ko * 8]) = bv;
    }
    __syncthreads();
    short8 a = af[ci].s;
#pragma unroll
    for (int t = 0; t < NT; ++t) {
      const short8 b = *(const short8*)(&B_lds[t * 16 * 40 + boff]);
      acc[t] = __builtin_amdgcn_mfma_f32_16x16x32_bf16(a, b, acc[t], 0, 0, 0);
    }
  }
  const int mrow = (lane >> 4) * 4;
#pragma unroll
  for (int t = 0; t < NT; ++t) {
    int col = t * 16 + (lane & 15);
    float bv = bias[col];
#pragma unroll
    for (int r = 0; r < 4; ++r) {
      int node = strip + w * 16 + mrow + r;
      if (node < M) out[(size_t)node * N_DIM + col] = f2bf(fmaxf(acc[t][r] + bv, 0.f));
    }
  }
}

// ---------------- GRU GEMM: barrier-free, LDS-free, 32x32/wave, 2-chunk software pipeline ----------------
// (measured 65 us @ MfmaUtil 11.5% in round 12; round-13 fusion with agg regressed to 172 us
//  by destroying the gather's L3 temporal locality -> keep split.)
__global__ __launch_bounds__(256)
void gru_gemm(const u16* __restrict__ agg, const u16* __restrict__ h,
              const u16* __restrict__ b2p, const float* __restrict__ b_ih,
              const float* __restrict__ b_hh, u16* __restrict__ hout, int M)
{
  const int tid  = threadIdx.x;
  const int lane = tid & 63;
  const int qc   = tid >> 6;              // col-quarter 0..3 (32 cols each)
  const int strip = blockIdx.x * 32;      // one 32-row strip per block (100000 % 32 == 0)
  const int lrow  = lane & 15;
  const int quad  = lane >> 4;
  const int ksub  = quad * 8;
  if (strip >= M) return;

  f32x4 ar[2][2], az[2][2], ain[2][2], ahn[2][2];
#pragma unroll
  for (int s = 0; s < 2; ++s)
#pragma unroll
    for (int t = 0; t < 2; ++t) {
      ar[s][t] = {0.f,0.f,0.f,0.f}; az[s][t] = {0.f,0.f,0.f,0.f};
      ain[s][t] = {0.f,0.f,0.f,0.f}; ahn[s][t] = {0.f,0.f,0.f,0.f};
    }

  union Frag { uint4 u; short8 s8; };
  const int node0 = strip + lrow;
  const int node1 = strip + 16 + lrow;
  const u16* bb = b2p + ((size_t)quad * 384 + qc * 32 + lrow) * 8;

  Frag a0[2], a1[2], fbr[2][2], fbz[2][2], fbg[2][2];

  auto ldchunk = [&](int ci, int p) {
    const u16* ap = (ci < 4) ? (agg + ci * 32 + ksub) : (h + (ci - 4) * 32 + ksub);
    a0[p].u = *(const uint4*)(ap + (size_t)node0 * 128);
    a1[p].u = *(const uint4*)(ap + (size_t)node1 * 128);
    const u16* cb = bb + ci * 12288;
    fbr[p][0].u = *(const uint4*)(cb);
    fbr[p][1].u = *(const uint4*)(cb + 128);
    fbz[p][0].u = *(const uint4*)(cb + 1024);
    fbz[p][1].u = *(const uint4*)(cb + 1024 + 128);
    fbg[p][0].u = *(const uint4*)(cb + 2048);
    fbg[p][1].u = *(const uint4*)(cb + 2048 + 128);
  };

  ldchunk(0, 0);
#pragma unroll
  for (int ci = 0; ci < 8; ++ci) {
    const int p = ci & 1, q = p ^ 1;
    if (ci < 7) ldchunk(ci + 1, q);   // prefetch next chunk before consuming current
#pragma unroll
    for (int t = 0; t < 2; ++t) {
      ar[0][t] = __builtin_amdgcn_mfma_f32_16x16x32_bf16(a0[p].s8, fbr[p][t].s8, ar[0][t], 0, 0, 0);
      ar[1][t] = __builtin_amdgcn_mfma_f32_16x16x32_bf16(a1[p].s8, fbr[p][t].s8, ar[1][t], 0, 0, 0);
      az[0][t] = __builtin_amdgcn_mfma_f32_16x16x32_bf16(a0[p].s8, fbz[p][t].s8, az[0][t], 0, 0, 0);
      az[1][t] = __builtin_amdgcn_mfma_f32_16x16x32_bf16(a1[p].s8, fbz[p][t].s8, az[1][t], 0, 0, 0);
    }
    if (ci < 4) {
#pragma unroll
      for (int t = 0; t < 2; ++t) {
        ain[0][t] = __builtin_amdgcn_mfma_f32_16x16x32_bf16(a0[p].s8, fbg[p][t].s8, ain[0][t], 0, 0, 0);
        ain[1][t] = __builtin_amdgcn_mfma_f32_16x16x32_bf16(a1[p].s8, fbg[p][t].s8, ain[1][t], 0, 0, 0);
      }
    } else {
#pragma unroll
      for (int t = 0; t < 2; ++t) {
        ahn[0][t] = __builtin_amdgcn_mfma_f32_16x16x32_bf16(a0[p].s8, fbg[p][t].s8, ahn[0][t], 0, 0, 0);
        ahn[1][t] = __builtin_amdgcn_mfma_f32_16x16x32_bf16(a1[p].s8, fbg[p][t].s8, ahn[1][t], 0, 0, 0);
      }
    }
  }

  // GRU epilogue. D layout per tile: row = quad*4 + r, col = lrow.
#pragma unroll
  for (int t = 0; t < 2; ++t) {
    const int c = qc * 32 + t * 16 + lrow;
    const float brr = b_ih[c] + b_hh[c];
    const float bzz = b_ih[128 + c] + b_hh[128 + c];
    const float bin = b_ih[256 + c];
    const float bhn = b_hh[256 + c];
#pragma unroll
    for (int s = 0; s < 2; ++s) {
#pragma unroll
      for (int r = 0; r < 4; ++r) {
        const int nrow = strip + s * 16 + quad * 4 + r;
        float rg = sigmoid_f(ar[s][t][r] + brr);
        float zg = sigmoid_f(az[s][t][r] + bzz);
        float hv = ahn[s][t][r] + bhn;
        float ng = tanh_f(ain[s][t][r] + bin + rg * hv);
        float hp = bf2f(h[(size_t)nrow * 128 + c]);
        hout[(size_t)nrow * 128 + c] = f2bf((1.f - zg) * ng + zg * hp);
      }
    }
  }
}

// ---------------- CSR aggregation, row-vectorized (dense pass keeps gather L3-hot) ----------------
__global__ __launch_bounds__(256)
void agg_kernel(const u16* __restrict__ m, const int* __restrict__ ssrc,
                const int* __restrict__ offsets, u16* __restrict__ agg)
{
  int node = blockIdx.x * 4 + (threadIdx.x >> 6);
  int lane = threadIdx.x & 63;
  if (node >= N_NODES) return;
  const int g = lane >> 4, l = lane & 15;
  int beg = offsets[node], end = offsets[node + 1];
  float s[8] = {0.f,0.f,0.f,0.f,0.f,0.f,0.f,0.f};
  for (int e = beg; e < end; e += 8) {   // 2 groups of 4 edges in flight
    uint4 v0 = {0u,0u,0u,0u}, v1 = {0u,0u,0u,0u};
    int e0 = e + g, e1 = e + 4 + g;
    if (e0 < end) { int src = ssrc[e0]; v0 = *(const uint4*)(m + (size_t)src * 128 + l * 8); }
    if (e1 < end) { int src = ssrc[e1]; v1 = *(const uint4*)(m + (size_t)src * 128 + l * 8); }
    u32 w0[4] = {v0.x, v0.y, v0.z, v0.w};
    u32 w1[4] = {v1.x, v1.y, v1.z, v1.w};
#pragma unroll
    for (int i = 0; i < 4; ++i) {
      s[2*i]   += bf2f((u16)(w0[i] & 0xffffu)) + bf2f((u16)(w1[i] & 0xffffu));
      s[2*i+1] += bf2f((u16)(w0[i] >> 16))     + bf2f((u16)(w1[i] >> 16));
    }
  }
#pragma unroll
  for (int i = 0; i < 8; ++i) {
    s[i] += __shfl_xor(s[i], 16, 64);
    s[i] += __shfl_xor(s[i], 32, 64);
  }
  if (g == 0) {
    uint4 o;
    o.x = (u32)f2bf(s[0]) | ((u32)f2bf(s[1]) << 16);
    o.y = (u32)f2bf(s[2]) | ((u32)f2bf(s[3]) << 16);
    o.z = (u32)f2bf(s[4]) | ((u32)f2bf(s[5]) << 16);
    o.w = (u32)f2bf(s[6]) | ((u32)f2bf(s[7]) << 16);
    *(uint4*)(agg + (size_t)node * 128 + l * 8) = o;
  }
}

// ---------------- parallel segmented mean-pool (batch is sorted) ----------------
__global__ __launch_bounds__(256)
void pool_kernel(const u16* __restrict__ h, const int* __restrict__ batch,
                 const int* __restrict__ flags, float* __restrict__ sums)
{
  const int c = threadIdx.x & 127;
  const int half = threadIdx.x >> 7;
  const int base = blockIdx.x * 128;
  const int f = flags[1];
  int gcur = -1; float s = 0.f;
  for (int i = half; i < 128; i += 2) {
    int n = base + i;
    if (n >= N_NODES) break;
    int g = geti(batch, n, f);
    if (g != gcur) {
      if (gcur >= 0) atomicAdd(&sums[gcur * 128 + c], s);
      s = 0.f; gcur = g;
    }
    s += bf2f(h[(size_t)n * 128 + c]);
  }
  if (gcur >= 0) atomicAdd(&sums[gcur * 128 + c], s);
}

// ---------------- doc proj + LN + fusion + heads, f32 (one block per graph) ----------------
__global__ __launch_bounds__(256)
void head2_kernel(const float* __restrict__ sums, const int* __restrict__ batch,
                  const int* __restrict__ flags,
                  const float* __restrict__ doc, const float* __restrict__ doc_w, const float* __restrict__ doc_b,
                  const float* __restrict__ ln_g, const float* __restrict__ ln_b,
                  const float* __restrict__ fus_w, const float* __restrict__ fus_b,
                  const float* __restrict__ task_w, const float* __restrict__ task_b,
                  const float* __restrict__ time_w, const float* __restrict__ time_b,
                  float* __restrict__ out_task, float* __restrict__ out_time)
{
  const int g = blockIdx.x;
  const int t = threadIdx.x;
  __shared__ float fusion[256];
  __shared__ float fh[128];
  __shared__ float dpart[256];
  __shared__ int seg[2];

  if (t < 2) {
    int f = flags[1];
    int target = g + t, lo = 0, hi = N_NODES;
    while (lo < hi) { int mid = (lo + hi) >> 1; if (geti(batch, mid, f) < target) lo = mid + 1; else hi = mid; }
    seg[t] = lo;
  }
  {
    int c = t & 127, kh = t >> 7;
    float s = 0.f;
    for (int k = kh * 384; k < kh * 384 + 384; ++k) s += doc[g * 768 + k] * doc_w[k * 128 + c];
    dpart[t] = s;
  }
  __syncthreads();

  if (t < 128) {
    float cnt = (float)(seg[1] - seg[0]);
    fusion[t] = sums[g * 128 + t] / fmaxf(cnt, 1.f);
  } else {
    int c = t - 128;
    fusion[t] = fmaxf(dpart[c] + dpart[c + 128] + doc_b[c], 0.f);
  }
  __syncthreads();

  float mu = 0.f;
  for (int i = 0; i < 256; ++i) mu += fusion[i];
  mu *= (1.f / 256.f);
  float var = 0.f;
  for (int i = 0; i < 256; ++i) { float d = fusion[i] - mu; var += d * d; }
  var *= (1.f / 256.f);
  float inv = rsqrtf(var + 1e-5f);
  float norm = (fusion[t] - mu) * inv * ln_g[t] + ln_b[t];
  __syncthreads();
  fusion[t] = norm;
  __syncthreads();

  if (t < 128) {
    float s = 0.f;
    for (int k = 0; k < 256; ++k) s += fusion[k] * fus_w[k * 128 + t];
    s += fus_b[t];
    fh[t] = fmaxf(s, 0.f);
  }
  __syncthreads();

  if (t < 32) {
    float s = 0.f;
    for (int k = 0; k < 128; ++k) s += fh[k] * task_w[k * 32 + t];
    s += task_b[t];
    out_task[g * 32 + t] = s;
  }
  if (t == 32) {
    float s = 0.f;
    for (int k = 0; k < 128; ++k) s += fh[k] * time_w[k];
    s += time_b[0];
    out_time[g] = s;
  }
}

// ---------------- launch ----------------
extern "C" void kernel_launch(void* const* d_in, const int* in_sizes, int n_in,
                              void* d_out, int out_size, void* d_ws, size_t ws_size,
                              hipStream_t stream)
{
  const float* x        = (const float*)d_in[0];
  const float* doc      = (const float*)d_in[1];
  const int*   ei       = (const int*)d_in[2];
  const int*   batch    = (const int*)d_in[3];
  const float* node_w   = (const float*)d_in[4];
  const float* node_b   = (const float*)d_in[5];
  const float* ggnn_w   = (const float*)d_in[6];
  const float* gru_w_ih = (const float*)d_in[7];
  const float* gru_b_ih = (const float*)d_in[8];
  const float* gru_w_hh = (const float*)d_in[9];
  const float* gru_b_hh = (const float*)d_in[10];
  const float* doc_w    = (const float*)d_in[11];
  const float* doc_b    = (const float*)d_in[12];
  const float* ln_g     = (const float*)d_in[13];
  const float* ln_b     = (const float*)d_in[14];
  const float* fus_w    = (const float*)d_in[15];
  const float* fus_b    = (const float*)d_in[16];
  const float* task_w   = (const float*)d_in[17];
  const float* task_b   = (const float*)d_in[18];
  const float* time_w   = (const float*)d_in[19];
  const float* time_b   = (const float*)d_in[20];

  char* ws = (char*)d_ws;
  size_t off = 0;
  auto alloc = [&](size_t bytes) -> void* {
    void* p = ws + off;
    off = (off + bytes + 255) & ~(size_t)255;
    return p;
  };
  u16* aggb    = (u16*)alloc((size_t)N_NODES * 128 * 2);
  u16* hA      = (u16*)alloc((size_t)N_NODES * 128 * 2);
  u16* hB      = (u16*)alloc((size_t)N_NODES * 128 * 2);
  u16* nwT     = (u16*)alloc(64 * 128 * 2);
  u16* b2p     = (u16*)alloc(3 * 8 * 1536 * 8 * 2);
  float* wp    = (float*)alloc(3 * 128 * 384 * 4);
  float* sums  = (float*)alloc(N_GRAPHS * 128 * 4);
  int* counts8 = (int*)alloc((size_t)8 * N_NODES * 4);
  int* px      = (int*)alloc((size_t)8 * N_NODES * 4);
  int* base8   = (int*)alloc((size_t)8 * N_NODES * 4);
  int* counts  = (int*)alloc((size_t)N_NODES * 4);
  int* offs    = (int*)alloc((size_t)(N_NODES + 1) * 4);
  int* ssrc    = (int*)alloc((size_t)N_EDGES * 4);
  u16* rankb   = (u16*)alloc((size_t)N_EDGES * 2);
  int* bsum    = (int*)alloc(SCAN_BLOCKS * 4);
  int* bbase   = (int*)alloc(SCAN_BLOCKS * 4);
  int* flags   = (int*)alloc(2 * 4);

  hipMemsetAsync(counts8, 0, (size_t)8 * N_NODES * 4, stream);
  hipMemsetAsync(sums, 0, (size_t)N_GRAPHS * 128 * 4, stream);

  detect_i64_kernel<<<1, 64, 0, stream>>>(ei, batch, flags);
  hist_kernel<<<(N_EDGES + 255) / 256, 256, 0, stream>>>(ei, flags, counts8, rankb);
  sum8_kernel<<<(N_NODES + 255) / 256, 256, 0, stream>>>(counts8, counts, px);
  scanA_kernel<<<SCAN_BLOCKS, 1024, 0, stream>>>(counts, bsum);
  scanB_kernel<<<1, 64, 0, stream>>>(bsum, bbase, offs);
  scanC_kernel<<<SCAN_BLOCKS, 1024, 0, stream>>>(counts, bbase, offs);
  base8_kernel<<<(8 * N_NODES + 255) / 256, 256, 0, stream>>>(offs, px, base8);
  scatter_kernel<<<(N_EDGES + 255) / 256, 256, 0, stream>>>(ei, flags, base8, rankb, ssrc);

  transpose_kernel<<<(64 * 128 + 255) / 256, 256, 0, stream>>>(node_w, nwT, 64, 128);
  wprime_kernel<<<(3 * 128 * 384 + 255) / 256, 256, 0, stream>>>(ggnn_w, gru_w_ih, wp);
  for (int l = 0; l < 3; ++l)
    build_b2p_kernel<<<(8 * 1536 * 8 + 255) / 256, 256, 0, stream>>>(
        wp + l * 128 * 384, gru_w_hh, b2p + (size_t)l * 8 * 1536 * 8);

  const int GB = (N_NODES + 63) / 64;    // 1563
  const int GB32 = N_NODES / 32;         // 3125
  nodeproj_gemm<<<GB, 256, 0, stream>>>(x, nwT, node_b, hA, N_NODES);

  u16* hcur = hA;
  u16* hnext = hB;
  for (int l = 0; l < 3; ++l) {
    agg_kernel<<<(N_NODES + 3) / 4, 256, 0, stream>>>(hcur, ssrc, offs, aggb);
    gru_gemm<<<GB32, 256, 0, stream>>>(aggb, hcur, b2p + (size_t)l * 8 * 1536 * 8,
                                       gru_b_ih, gru_b_hh, hnext, N_NODES);
    u16* tmp = hcur; hcur = hnext; hnext = tmp;
  }

  pool_kernel<<<(N_NODES + 127) / 128, 256, 0, stream>>>(hcur, batch, flags, sums);

  float* out_task = (float*)d_out;
  float* out_time = out_task + N_GRAPHS * 32;
  head2_kernel<<<N_GRAPHS, 256, 0, stream>>>(sums, batch, flags, doc, doc_w, doc_b, ln_g, ln_b,
                                             fus_w, fus_b, task_w, task_b, time_w, time_b,
                                             out_task, out_time);
}

// Round 15
// 677.751 us; speedup vs baseline: 1.1843x; 1.0041x over previous
//
#include <hip/hip_runtime.h>

#define N_NODES  100000
#define N_EDGES  1600000
#define N_GRAPHS 128
#define SCAN_BLOCKS 98   // ceil(100000/1024)

typedef unsigned short u16;
typedef unsigned int   u32;
typedef __attribute__((ext_vector_type(8))) short short8;
typedef __attribute__((ext_vector_type(4))) float f32x4;

__device__ __forceinline__ float bf2f(u16 v) {
  union { u32 i; float f; } u; u.i = ((u32)v) << 16; return u.f;
}
__device__ __forceinline__ u16 f2bf(float f) {
  union { float f; u32 i; } u; u.f = f;
  u32 r = (u.i + 0x7fffu + ((u.i >> 16) & 1u)) >> 16;
  return (u16)r;
}
__device__ __forceinline__ float sigmoid_f(float x) { return 1.f / (1.f + __expf(-x)); }
__device__ __forceinline__ float tanh_f(float x) {
  x = fminf(15.f, fmaxf(-15.f, x));
  float e = __expf(2.f * x);
  return (e - 1.f) / (e + 1.f);
}
__device__ __forceinline__ int geti(const int* __restrict__ p, int i, int is64) {
  return p[is64 ? (2 * i) : i];
}

// Detect whether edge_index / batch are int64 (all sampled odd words == 0) or int32.
__global__ void detect_i64_kernel(const int* __restrict__ ei, const int* __restrict__ batch,
                                  int* __restrict__ flags) {
  int lane = threadIdx.x;  // 64
  {
    long long q = (long long)lane * (3200000 / 2 - 1) / 63;
    int pos = (int)(2 * q + 1);
    unsigned long long m = __ballot(ei[pos] != 0);
    if (lane == 0) flags[0] = (m == 0ull) ? 1 : 0;
  }
  {
    long long q = (long long)lane * (100000 / 2 - 1) / 63;
    int pos = (int)(2 * q + 1);
    unsigned long long m = __ballot(batch[pos] != 0);
    if (lane == 0) flags[1] = (m == 0ull) ? 1 : 0;
  }
}

// ---------------- CSR build ----------------
// XCD-localized histogram (round 12: removed 53 MB of cross-XCD atomic line ping-pong).
__global__ void hist_kernel(const int* __restrict__ ei, const int* __restrict__ flags,
                            int* __restrict__ counts8, u16* __restrict__ rankb) {
  int e = blockIdx.x * 256 + threadIdx.x;
  if (e < N_EDGES) {
    int f = flags[0];
    int d = geti(ei, N_EDGES + e, f);
    int g = blockIdx.x & 7;
    int r = atomicAdd(&counts8[g * N_NODES + d], 1);
    rankb[e] = (u16)(r | (g << 12));   // per-(g,d) rank < 4096
  }
}

// scanA: per-block sum of per-node totals (reads counts8 directly; sum8 fused away).
__global__ __launch_bounds__(1024)
void scanA_kernel(const int* __restrict__ counts8, int* __restrict__ blocksums) {
  __shared__ int red[16];
  int i = blockIdx.x * 1024 + threadIdx.x;
  int v = 0;
  if (i < N_NODES) {
#pragma unroll
    for (int g = 0; g < 8; ++g) v += counts8[g * N_NODES + i];
  }
  for (int o = 32; o > 0; o >>= 1) v += __shfl_down(v, o, 64);
  int wv = threadIdx.x >> 6, lane = threadIdx.x & 63;
  if (lane == 0) red[wv] = v;
  __syncthreads();
  if (threadIdx.x < 16) {
    int s = red[threadIdx.x];
    for (int o = 8; o > 0; o >>= 1) s += __shfl_down(s, o, 64);
    if (threadIdx.x == 0) blocksums[blockIdx.x] = s;
  }
}

__global__ void scanB_kernel(const int* __restrict__ blocksums, int* __restrict__ blockbase,
                             int* __restrict__ offsets) {
  if (threadIdx.x == 0) {
    int run = 0;
    for (int b = 0; b < SCAN_BLOCKS; ++b) { blockbase[b] = run; run += blocksums[b]; }
    offsets[N_NODES] = run;
  }
}

// scanC: exclusive offsets + packed nodeinfo[d] = {offs:u32, px[8]:u8, pad:u32}.
// px[g] = prefix of counts8 over groups (<= degree <= ~60, fits u8). Scatter then
// needs ONE 16-B random read from a 1.6 MB L2-resident array (round 14's base8 was
// a 3.2 MB random-read set -> extra L3-latency hits on 1.6M dependent reads).
__global__ __launch_bounds__(1024)
void scanC_kernel(const int* __restrict__ counts8, const int* __restrict__ blockbase,
                  int* __restrict__ offsets, uint4* __restrict__ nodeinfo) {
  __shared__ int buf[1024];
  int t = threadIdx.x;
  int i = blockIdx.x * 1024 + t;
  int c8[8];
  int v = 0;
  if (i < N_NODES) {
#pragma unroll
    for (int g = 0; g < 8; ++g) { c8[g] = counts8[g * N_NODES + i]; v += c8[g]; }
  }
  buf[t] = v;
  __syncthreads();
  for (int o = 1; o < 1024; o <<= 1) {
    int add = (t >= o) ? buf[t - o] : 0;
    __syncthreads();
    buf[t] += add;
    __syncthreads();
  }
  if (i < N_NODES) {
    int offs = buf[t] - v + blockbase[blockIdx.x];
    offsets[i] = offs;
    u32 lo = 0, hi = 0; int run = 0;
#pragma unroll
    for (int g = 0; g < 4; ++g) { lo |= (u32)(run & 0xff) << (8 * g); run += c8[g]; }
#pragma unroll
    for (int g = 4; g < 8; ++g) { hi |= (u32)(run & 0xff) << (8 * (g - 4)); run += c8[g]; }
    uint4 info; info.x = (u32)offs; info.y = lo; info.z = hi; info.w = 0u;
    nodeinfo[i] = info;
  }
}

// atomic-free scatter: one 16-B random read per edge.
__global__ void scatter_kernel(const int* __restrict__ ei, const int* __restrict__ flags,
                               const uint4* __restrict__ nodeinfo, const u16* __restrict__ rankb,
                               int* __restrict__ ssrc) {
  int e = blockIdx.x * 256 + threadIdx.x;
  if (e < N_EDGES) {
    int f = flags[0];
    int d = geti(ei, N_EDGES + e, f);
    int pr = (int)rankb[e];
    int g = pr >> 12, r = pr & 0xfff;
    uint4 info = nodeinfo[d];
    int px = (g < 4) ? (int)((info.y >> (8 * g)) & 0xffu)
                     : (int)((info.z >> (8 * (g - 4))) & 0xffu);
    ssrc[(int)info.x + px + r] = geti(ei, e, f);
  }
}

// ---------------- weight prep ----------------
// f32 [K][N] row-major -> bf16 [N][K]
__global__ void transpose_kernel(const float* __restrict__ in, u16* __restrict__ out, int K, int N) {
  int i = blockIdx.x * 256 + threadIdx.x;
  if (i < K * N) {
    int k = i / N, n = i % N;
    out[n * K + k] = f2bf(in[i]);
  }
}

// W'_l[k][c] = sum_j ggnn_w[l][k][j] * w_ih[j][c]   (f32, [3][128][384])
__global__ void wprime_kernel(const float* __restrict__ ggnn_w, const float* __restrict__ w_ih,
                              float* __restrict__ wp) {
  int i = blockIdx.x * 256 + threadIdx.x;
  if (i >= 3 * 128 * 384) return;
  int l = i / (128 * 384), r = i % (128 * 384), k = r / 384, c = r % 384;
  const float* W = ggnn_w + l * 128 * 128;
  float s = 0.f;
  for (int j = 0; j < 128; ++j) s += W[k * 128 + j] * w_ih[j * 384 + c];
  wp[i] = s;
}

// Packed GRU weight, ALL 3 layers in one launch: b2p[l][ci][idx][e] u16.
// Zero quadrants excluded (ci<4: W' cols r|z|in; ci>=4: w_hh cols r|z|hn).
__global__ void build_b2p_kernel(const float* __restrict__ wp, const float* __restrict__ w_hh,
                                 u16* __restrict__ b2p) {
  int g = blockIdx.x * 256 + threadIdx.x;
  if (g >= 3 * 8 * 1536 * 8) return;
  int l = g / (8 * 1536 * 8);
  int rem = g % (8 * 1536 * 8);
  int e = rem & 7;
  int grp = rem >> 3;
  int ci = grp / 1536;
  int idx = grp % 1536;
  int n_lin = idx % 384;
  int ko = idx / 384;
  int k = ci * 32 + ko * 8 + e;
  float v = (k < 128) ? wp[l * 128 * 384 + k * 384 + n_lin] : w_hh[(k - 128) * 384 + n_lin];
  b2p[g] = f2bf(v);
}

// ---------------- node projection GEMM (f32 A -> bf16 frags) ----------------
__global__ __launch_bounds__(256)
void nodeproj_gemm(const float* __restrict__ A, const u16* __restrict__ BT,
                   const float* __restrict__ bias, u16* __restrict__ out, int M)
{
  constexpr int K_DIM = 64, N_DIM = 128, NT = 8, NCHUNK = 2;
  __shared__ u16 B_lds[N_DIM * 40];
  const int tid = threadIdx.x, lane = tid & 63, w = tid >> 6;
  const int strip = blockIdx.x * 64;
  const int ksub = (lane >> 4) * 8;
  union Frag { uint4 u; short8 s; };
  Frag af[NCHUNK];
  const int m_node = strip + w * 16 + (lane & 15);
  const bool avalid = (m_node < M);
#pragma unroll
  for (int ci = 0; ci < NCHUNK; ++ci) {
    int k0 = ci * 32 + ksub;
    short8 sv = {0,0,0,0,0,0,0,0};
    if (avalid) {
      const float* p = A + (size_t)m_node * K_DIM + k0;
      float4 f0 = *(const float4*)p;
      float4 f1 = *(const float4*)(p + 4);
      sv[0]=(short)f2bf(f0.x); sv[1]=(short)f2bf(f0.y); sv[2]=(short)f2bf(f0.z); sv[3]=(short)f2bf(f0.w);
      sv[4]=(short)f2bf(f1.x); sv[5]=(short)f2bf(f1.y); sv[6]=(short)f2bf(f1.z); sv[7]=(short)f2bf(f1.w);
    }
    af[ci].s = sv;
  }
  f32x4 acc[NT];
#pragma unroll
  for (int t = 0; t < NT; ++t) acc[t] = {0.f, 0.f, 0.f, 0.f};
  const int boff = (lane & 15) * 40 + ksub;
#pragma unroll
  for (int ci = 0; ci < NCHUNK; ++ci) {
    if (ci) __syncthreads();
    for (int g = tid; g < N_DIM * 4; g += 256) {
      int n = g >> 2, ko = g & 3;
      uint4 bv = *(const uint4*)(BT + (size_t)n * K_DIM + ci * 32 + ko * 8);
      *(uint4*)(&B_lds[n * 40 + ko * 8]) = bv;
    }
    __syncthreads();
    short8 a = af[ci].s;
#pragma unroll
    for (int t = 0; t < NT; ++t) {
      const short8 b = *(const short8*)(&B_lds[t * 16 * 40 + boff]);
      acc[t] = __builtin_amdgcn_mfma_f32_16x16x32_bf16(a, b, acc[t], 0, 0, 0);
    }
  }
  const int mrow = (lane >> 4) * 4;
#pragma unroll
  for (int t = 0; t < NT; ++t) {
    int col = t * 16 + (lane & 15);
    float bv = bias[col];
#pragma unroll
    for (int r = 0; r < 4; ++r) {
      int node = strip + w * 16 + mrow + r;
      if (node < M) out[(size_t)node * N_DIM + col] = f2bf(fmaxf(acc[t][r] + bv, 0.f));
    }
  }
}

// ---------------- GRU GEMM: barrier-free, LDS-free, 32x32/wave, 2-chunk software pipeline ----------------
// (measured 65 us @ MfmaUtil 11.5%; latency-bound, L2-BW floor ~10 us; shape/pipeline
//  variants all land 65-80 -> keep. Round-13 fusion with agg regressed to 172 us.)
__global__ __launch_bounds__(256)
void gru_gemm(const u16* __restrict__ agg, const u16* __restrict__ h,
              const u16* __restrict__ b2p, const float* __restrict__ b_ih,
              const float* __restrict__ b_hh, u16* __restrict__ hout, int M)
{
  const int tid  = threadIdx.x;
  const int lane = tid & 63;
  const int qc   = tid >> 6;              // col-quarter 0..3 (32 cols each)
  const int strip = blockIdx.x * 32;      // one 32-row strip per block (100000 % 32 == 0)
  const int lrow  = lane & 15;
  const int quad  = lane >> 4;
  const int ksub  = quad * 8;
  if (strip >= M) return;

  f32x4 ar[2][2], az[2][2], ain[2][2], ahn[2][2];
#pragma unroll
  for (int s = 0; s < 2; ++s)
#pragma unroll
    for (int t = 0; t < 2; ++t) {
      ar[s][t] = {0.f,0.f,0.f,0.f}; az[s][t] = {0.f,0.f,0.f,0.f};
      ain[s][t] = {0.f,0.f,0.f,0.f}; ahn[s][t] = {0.f,0.f,0.f,0.f};
    }

  union Frag { uint4 u; short8 s8; };
  const int node0 = strip + lrow;
  const int node1 = strip + 16 + lrow;
  const u16* bb = b2p + ((size_t)quad * 384 + qc * 32 + lrow) * 8;

  Frag a0[2], a1[2], fbr[2][2], fbz[2][2], fbg[2][2];

  auto ldchunk = [&](int ci, int p) {
    const u16* ap = (ci < 4) ? (agg + ci * 32 + ksub) : (h + (ci - 4) * 32 + ksub);
    a0[p].u = *(const uint4*)(ap + (size_t)node0 * 128);
    a1[p].u = *(const uint4*)(ap + (size_t)node1 * 128);
    const u16* cb = bb + ci * 12288;
    fbr[p][0].u = *(const uint4*)(cb);
    fbr[p][1].u = *(const uint4*)(cb + 128);
    fbz[p][0].u = *(const uint4*)(cb + 1024);
    fbz[p][1].u = *(const uint4*)(cb + 1024 + 128);
    fbg[p][0].u = *(const uint4*)(cb + 2048);
    fbg[p][1].u = *(const uint4*)(cb + 2048 + 128);
  };

  ldchunk(0, 0);
#pragma unroll
  for (int ci = 0; ci < 8; ++ci) {
    const int p = ci & 1, q = p ^ 1;
    if (ci < 7) ldchunk(ci + 1, q);   // prefetch next chunk before consuming current
#pragma unroll
    for (int t = 0; t < 2; ++t) {
      ar[0][t] = __builtin_amdgcn_mfma_f32_16x16x32_bf16(a0[p].s8, fbr[p][t].s8, ar[0][t], 0, 0, 0);
      ar[1][t] = __builtin_amdgcn_mfma_f32_16x16x32_bf16(a1[p].s8, fbr[p][t].s8, ar[1][t], 0, 0, 0);
      az[0][t] = __builtin_amdgcn_mfma_f32_16x16x32_bf16(a0[p].s8, fbz[p][t].s8, az[0][t], 0, 0, 0);
      az[1][t] = __builtin_amdgcn_mfma_f32_16x16x32_bf16(a1[p].s8, fbz[p][t].s8, az[1][t], 0, 0, 0);
    }
    if (ci < 4) {
#pragma unroll
      for (int t = 0; t < 2; ++t) {
        ain[0][t] = __builtin_amdgcn_mfma_f32_16x16x32_bf16(a0[p].s8, fbg[p][t].s8, ain[0][t], 0, 0, 0);
        ain[1][t] = __builtin_amdgcn_mfma_f32_16x16x32_bf16(a1[p].s8, fbg[p][t].s8, ain[1][t], 0, 0, 0);
      }
    } else {
#pragma unroll
      for (int t = 0; t < 2; ++t) {
        ahn[0][t] = __builtin_amdgcn_mfma_f32_16x16x32_bf16(a0[p].s8, fbg[p][t].s8, ahn[0][t], 0, 0, 0);
        ahn[1][t] = __builtin_amdgcn_mfma_f32_16x16x32_bf16(a1[p].s8, fbg[p][t].s8, ahn[1][t], 0, 0, 0);
      }
    }
  }

  // GRU epilogue. D layout per tile: row = quad*4 + r, col = lrow.
#pragma unroll
  for (int t = 0; t < 2; ++t) {
    const int c = qc * 32 + t * 16 + lrow;
    const float brr = b_ih[c] + b_hh[c];
    const float bzz = b_ih[128 + c] + b_hh[128 + c];
    const float bin = b_ih[256 + c];
    const float bhn = b_hh[256 + c];
#pragma unroll
    for (int s = 0; s < 2; ++s) {
#pragma unroll
      for (int r = 0; r < 4; ++r) {
        const int nrow = strip + s * 16 + quad * 4 + r;
        float rg = sigmoid_f(ar[s][t][r] + brr);
        float zg = sigmoid_f(az[s][t][r] + bzz);
        float hv = ahn[s][t][r] + bhn;
        float ng = tanh_f(ain[s][t][r] + bin + rg * hv);
        float hp = bf2f(h[(size_t)nrow * 128 + c]);
        hout[(size_t)nrow * 128 + c] = f2bf((1.f - zg) * ng + zg * hp);
      }
    }
  }
}

// ---------------- CSR aggregation, row-vectorized (dense pass keeps gather L3-hot) ----------------
__global__ __launch_bounds__(256)
void agg_kernel(const u16* __restrict__ m, const int* __restrict__ ssrc,
                const int* __restrict__ offsets, u16* __restrict__ agg)
{
  int node = blockIdx.x * 4 + (threadIdx.x >> 6);
  int lane = threadIdx.x & 63;
  if (node >= N_NODES) return;
  const int g = lane >> 4, l = lane & 15;
  int beg = offsets[node], end = offsets[node + 1];
  float s[8] = {0.f,0.f,0.f,0.f,0.f,0.f,0.f,0.f};
  for (int e = beg; e < end; e += 8) {   // 2 groups of 4 edges in flight
    uint4 v0 = {0u,0u,0u,0u}, v1 = {0u,0u,0u,0u};
    int e0 = e + g, e1 = e + 4 + g;
    if (e0 < end) { int src = ssrc[e0]; v0 = *(const uint4*)(m + (size_t)src * 128 + l * 8); }
    if (e1 < end) { int src = ssrc[e1]; v1 = *(const uint4*)(m + (size_t)src * 128 + l * 8); }
    u32 w0[4] = {v0.x, v0.y, v0.z, v0.w};
    u32 w1[4] = {v1.x, v1.y, v1.z, v1.w};
#pragma unroll
    for (int i = 0; i < 4; ++i) {
      s[2*i]   += bf2f((u16)(w0[i] & 0xffffu)) + bf2f((u16)(w1[i] & 0xffffu));
      s[2*i+1] += bf2f((u16)(w0[i] >> 16))     + bf2f((u16)(w1[i] >> 16));
    }
  }
#pragma unroll
  for (int i = 0; i < 8; ++i) {
    s[i] += __shfl_xor(s[i], 16, 64);
    s[i] += __shfl_xor(s[i], 32, 64);
  }
  if (g == 0) {
    uint4 o;
    o.x = (u32)f2bf(s[0]) | ((u32)f2bf(s[1]) << 16);
    o.y = (u32)f2bf(s[2]) | ((u32)f2bf(s[3]) << 16);
    o.z = (u32)f2bf(s[4]) | ((u32)f2bf(s[5]) << 16);
    o.w = (u32)f2bf(s[6]) | ((u32)f2bf(s[7]) << 16);
    *(uint4*)(agg + (size_t)node * 128 + l * 8) = o;
  }
}

// ---------------- parallel segmented mean-pool (batch is sorted) ----------------
__global__ __launch_bounds__(256)
void pool_kernel(const u16* __restrict__ h, const int* __restrict__ batch,
                 const int* __restrict__ flags, float* __restrict__ sums)
{
  const int c = threadIdx.x & 127;
  const int half = threadIdx.x >> 7;
  const int base = blockIdx.x * 128;
  const int f = flags[1];
  int gcur = -1; float s = 0.f;
  for (int i = half; i < 128; i += 2) {
    int n = base + i;
    if (n >= N_NODES) break;
    int g = geti(batch, n, f);
    if (g != gcur) {
      if (gcur >= 0) atomicAdd(&sums[gcur * 128 + c], s);
      s = 0.f; gcur = g;
    }
    s += bf2f(h[(size_t)n * 128 + c]);
  }
  if (gcur >= 0) atomicAdd(&sums[gcur * 128 + c], s);
}

// ---------------- doc proj + LN + fusion + heads, f32 (one block per graph) ----------------
__global__ __launch_bounds__(256)
void head2_kernel(const float* __restrict__ sums, const int* __restrict__ batch,
                  const int* __restrict__ flags,
                  const float* __restrict__ doc, const float* __restrict__ doc_w, const float* __restrict__ doc_b,
                  const float* __restrict__ ln_g, const float* __restrict__ ln_b,
                  const float* __restrict__ fus_w, const float* __restrict__ fus_b,
                  const float* __restrict__ task_w, const float* __restrict__ task_b,
                  const float* __restrict__ time_w, const float* __restrict__ time_b,
                  float* __restrict__ out_task, float* __restrict__ out_time)
{
  const int g = blockIdx.x;
  const int t = threadIdx.x;
  __shared__ float fusion[256];
  __shared__ float fh[128];
  __shared__ float dpart[256];
  __shared__ int seg[2];

  if (t < 2) {
    int f = flags[1];
    int target = g + t, lo = 0, hi = N_NODES;
    while (lo < hi) { int mid = (lo + hi) >> 1; if (geti(batch, mid, f) < target) lo = mid + 1; else hi = mid; }
    seg[t] = lo;
  }
  {
    int c = t & 127, kh = t >> 7;
    float s = 0.f;
    for (int k = kh * 384; k < kh * 384 + 384; ++k) s += doc[g * 768 + k] * doc_w[k * 128 + c];
    dpart[t] = s;
  }
  __syncthreads();

  if (t < 128) {
    float cnt = (float)(seg[1] - seg[0]);
    fusion[t] = sums[g * 128 + t] / fmaxf(cnt, 1.f);
  } else {
    int c = t - 128;
    fusion[t] = fmaxf(dpart[c] + dpart[c + 128] + doc_b[c], 0.f);
  }
  __syncthreads();

  float mu = 0.f;
  for (int i = 0; i < 256; ++i) mu += fusion[i];
  mu *= (1.f / 256.f);
  float var = 0.f;
  for (int i = 0; i < 256; ++i) { float d = fusion[i] - mu; var += d * d; }
  var *= (1.f / 256.f);
  float inv = rsqrtf(var + 1e-5f);
  float norm = (fusion[t] - mu) * inv * ln_g[t] + ln_b[t];
  __syncthreads();
  fusion[t] = norm;
  __syncthreads();

  if (t < 128) {
    float s = 0.f;
    for (int k = 0; k < 256; ++k) s += fusion[k] * fus_w[k * 128 + t];
    s += fus_b[t];
    fh[t] = fmaxf(s, 0.f);
  }
  __syncthreads();

  if (t < 32) {
    float s = 0.f;
    for (int k = 0; k < 128; ++k) s += fh[k] * task_w[k * 32 + t];
    s += task_b[t];
    out_task[g * 32 + t] = s;
  }
  if (t == 32) {
    float s = 0.f;
    for (int k = 0; k < 128; ++k) s += fh[k] * time_w[k];
    s += time_b[0];
    out_time[g] = s;
  }
}

// ---------------- launch ----------------
extern "C" void kernel_launch(void* const* d_in, const int* in_sizes, int n_in,
                              void* d_out, int out_size, void* d_ws, size_t ws_size,
                              hipStream_t stream)
{
  const float* x        = (const float*)d_in[0];
  const float* doc      = (const float*)d_in[1];
  const int*   ei       = (const int*)d_in[2];
  const int*   batch    = (const int*)d_in[3];
  const float* node_w   = (const float*)d_in[4];
  const float* node_b   = (const float*)d_in[5];
  const float* ggnn_w   = (const float*)d_in[6];
  const float* gru_w_ih = (const float*)d_in[7];
  const float* gru_b_ih = (const float*)d_in[8];
  const float* gru_w_hh = (const float*)d_in[9];
  const float* gru_b_hh = (const float*)d_in[10];
  const float* doc_w    = (const float*)d_in[11];
  const float* doc_b    = (const float*)d_in[12];
  const float* ln_g     = (const float*)d_in[13];
  const float* ln_b     = (const float*)d_in[14];
  const float* fus_w    = (const float*)d_in[15];
  const float* fus_b    = (const float*)d_in[16];
  const float* task_w   = (const float*)d_in[17];
  const float* task_b   = (const float*)d_in[18];
  const float* time_w   = (const float*)d_in[19];
  const float* time_b   = (const float*)d_in[20];

  char* ws = (char*)d_ws;
  size_t off = 0;
  auto alloc = [&](size_t bytes) -> void* {
    void* p = ws + off;
    off = (off + bytes + 255) & ~(size_t)255;
    return p;
  };
  u16* aggb     = (u16*)alloc((size_t)N_NODES * 128 * 2);
  u16* hA       = (u16*)alloc((size_t)N_NODES * 128 * 2);
  u16* hB       = (u16*)alloc((size_t)N_NODES * 128 * 2);
  u16* nwT      = (u16*)alloc(64 * 128 * 2);
  u16* b2p      = (u16*)alloc(3 * 8 * 1536 * 8 * 2);
  float* wp     = (float*)alloc(3 * 128 * 384 * 4);
  float* sums   = (float*)alloc(N_GRAPHS * 128 * 4);
  int* counts8  = (int*)alloc((size_t)8 * N_NODES * 4);
  uint4* ninfo  = (uint4*)alloc((size_t)N_NODES * 16);
  int* offs     = (int*)alloc((size_t)(N_NODES + 1) * 4);
  int* ssrc     = (int*)alloc((size_t)N_EDGES * 4);
  u16* rankb    = (u16*)alloc((size_t)N_EDGES * 2);
  int* bsum     = (int*)alloc(SCAN_BLOCKS * 4);
  int* bbase    = (int*)alloc(SCAN_BLOCKS * 4);
  int* flags    = (int*)alloc(2 * 4);

  hipMemsetAsync(counts8, 0, (size_t)8 * N_NODES * 4, stream);
  hipMemsetAsync(sums, 0, (size_t)N_GRAPHS * 128 * 4, stream);

  detect_i64_kernel<<<1, 64, 0, stream>>>(ei, batch, flags);
  hist_kernel<<<(N_EDGES + 255) / 256, 256, 0, stream>>>(ei, flags, counts8, rankb);
  scanA_kernel<<<SCAN_BLOCKS, 1024, 0, stream>>>(counts8, bsum);
  scanB_kernel<<<1, 64, 0, stream>>>(bsum, bbase, offs);
  scanC_kernel<<<SCAN_BLOCKS, 1024, 0, stream>>>(counts8, bbase, offs, ninfo);
  scatter_kernel<<<(N_EDGES + 255) / 256, 256, 0, stream>>>(ei, flags, ninfo, rankb, ssrc);

  transpose_kernel<<<(64 * 128 + 255) / 256, 256, 0, stream>>>(node_w, nwT, 64, 128);
  wprime_kernel<<<(3 * 128 * 384 + 255) / 256, 256, 0, stream>>>(ggnn_w, gru_w_ih, wp);
  build_b2p_kernel<<<(3 * 8 * 1536 * 8 + 255) / 256, 256, 0, stream>>>(wp, gru_w_hh, b2p);

  const int GB = (N_NODES + 63) / 64;    // 1563
  const int GB32 = N_NODES / 32;         // 3125
  nodeproj_gemm<<<GB, 256, 0, stream>>>(x, nwT, node_b, hA, N_NODES);

  u16* hcur = hA;
  u16* hnext = hB;
  for (int l = 0; l < 3; ++l) {
    agg_kernel<<<(N_NODES + 3) / 4, 256, 0, stream>>>(hcur, ssrc, offs, aggb);
    gru_gemm<<<GB32, 256, 0, stream>>>(aggb, hcur, b2p + (size_t)l * 8 * 1536 * 8,
                                       gru_b_ih, gru_b_hh, hnext, N_NODES);
    u16* tmp = hcur; hcur = hnext; hnext = tmp;
  }

  pool_kernel<<<(N_NODES + 127) / 128, 256, 0, stream>>>(hcur, batch, flags, sums);

  float* out_task = (float*)d_out;
  float* out_time = out_task + N_GRAPHS * 32;
  head2_kernel<<<N_GRAPHS, 256, 0, stream>>>(sums, batch, flags, doc, doc_w, doc_b, ln_g, ln_b,
                                             fus_w, fus_b, task_w, task_b, time_w, time_b,
                                             out_task, out_time);
}

// Round 16
// 670.276 us; speedup vs baseline: 1.1975x; 1.0112x over previous
//
#include <hip/hip_runtime.h>

#define N_NODES  100000
#define N_EDGES  1600000
#define N_GRAPHS 128
#define SCAN_BLOCKS 98   // ceil(100000/1024)

typedef unsigned short u16;
typedef unsigned int   u32;
typedef __attribute__((ext_vector_type(8))) short short8;
typedef __attribute__((ext_vector_type(4))) float f32x4;

__device__ __forceinline__ float bf2f(u16 v) {
  union { u32 i; float f; } u; u.i = ((u32)v) << 16; return u.f;
}
__device__ __forceinline__ u16 f2bf(float f) {
  union { float f; u32 i; } u; u.f = f;
  u32 r = (u.i + 0x7fffu + ((u.i >> 16) & 1u)) >> 16;
  return (u16)r;
}
__device__ __forceinline__ float sigmoid_f(float x) { return 1.f / (1.f + __expf(-x)); }
__device__ __forceinline__ float tanh_f(float x) {
  x = fminf(15.f, fmaxf(-15.f, x));
  float e = __expf(2.f * x);
  return (e - 1.f) / (e + 1.f);
}
__device__ __forceinline__ int geti(const int* __restrict__ p, int i, int is64) {
  return p[is64 ? (2 * i) : i];
}

// Detect whether edge_index / batch are int64 (all sampled odd words == 0) or int32.
__global__ void detect_i64_kernel(const int* __restrict__ ei, const int* __restrict__ batch,
                                  int* __restrict__ flags) {
  int lane = threadIdx.x;  // 64
  {
    long long q = (long long)lane * (3200000 / 2 - 1) / 63;
    int pos = (int)(2 * q + 1);
    unsigned long long m = __ballot(ei[pos] != 0);
    if (lane == 0) flags[0] = (m == 0ull) ? 1 : 0;
  }
  {
    long long q = (long long)lane * (100000 / 2 - 1) / 63;
    int pos = (int)(2 * q + 1);
    unsigned long long m = __ballot(batch[pos] != 0);
    if (lane == 0) flags[1] = (m == 0ull) ? 1 : 0;
  }
}

// ---------------- CSR build (round-11 measured-best path) ----------------
// hist records each edge's rank among its dst's edges -> scatter needs no atomics.
// NOTE (r12-r15 A/B): XCD-localized counts8 variants cut hist 68->~15 us but lost more in
// sum8/scan/scatter working-set growth (667 -> 680 net). Single counts + rankb is net-best.
__global__ void hist_kernel(const int* __restrict__ ei, const int* __restrict__ flags,
                            int* __restrict__ counts, u16* __restrict__ rankb) {
  int e = blockIdx.x * 256 + threadIdx.x;
  if (e < N_EDGES) {
    int f = flags[0];
    int d = geti(ei, N_EDGES + e, f);
    int r = atomicAdd(&counts[d], 1);
    rankb[e] = (u16)r;
  }
}

__global__ __launch_bounds__(1024)
void scanA_kernel(const int* __restrict__ counts, int* __restrict__ blocksums) {
  __shared__ int red[16];
  int i = blockIdx.x * 1024 + threadIdx.x;
  int v = (i < N_NODES) ? counts[i] : 0;
  for (int o = 32; o > 0; o >>= 1) v += __shfl_down(v, o, 64);
  int wv = threadIdx.x >> 6, lane = threadIdx.x & 63;
  if (lane == 0) red[wv] = v;
  __syncthreads();
  if (threadIdx.x < 16) {
    int s = red[threadIdx.x];
    for (int o = 8; o > 0; o >>= 1) s += __shfl_down(s, o, 64);
    if (threadIdx.x == 0) blocksums[blockIdx.x] = s;
  }
}

__global__ void scanB_kernel(const int* __restrict__ blocksums, int* __restrict__ blockbase,
                             int* __restrict__ offsets) {
  if (threadIdx.x == 0) {
    int run = 0;
    for (int b = 0; b < SCAN_BLOCKS; ++b) { blockbase[b] = run; run += blocksums[b]; }
    offsets[N_NODES] = run;
  }
}

__global__ __launch_bounds__(1024)
void scanC_kernel(const int* __restrict__ counts, const int* __restrict__ blockbase,
                  int* __restrict__ offsets) {
  __shared__ int buf[1024];
  int t = threadIdx.x;
  int i = blockIdx.x * 1024 + t;
  int v = (i < N_NODES) ? counts[i] : 0;
  buf[t] = v;
  __syncthreads();
  for (int o = 1; o < 1024; o <<= 1) {
    int add = (t >= o) ? buf[t - o] : 0;
    __syncthreads();
    buf[t] += add;
    __syncthreads();
  }
  if (i < N_NODES) offsets[i] = buf[t] - v + blockbase[blockIdx.x];
}

// atomic-free scatter: one 4-B random read from the 400 KB L1/L2-resident offsets.
__global__ void scatter_kernel(const int* __restrict__ ei, const int* __restrict__ flags,
                               const int* __restrict__ offsets, const u16* __restrict__ rankb,
                               int* __restrict__ ssrc) {
  int e = blockIdx.x * 256 + threadIdx.x;
  if (e < N_EDGES) {
    int f = flags[0];
    int d = geti(ei, N_EDGES + e, f);
    ssrc[offsets[d] + (int)rankb[e]] = geti(ei, e, f);
  }
}

// ---------------- weight prep ----------------
// f32 [K][N] row-major -> bf16 [N][K]
__global__ void transpose_kernel(const float* __restrict__ in, u16* __restrict__ out, int K, int N) {
  int i = blockIdx.x * 256 + threadIdx.x;
  if (i < K * N) {
    int k = i / N, n = i % N;
    out[n * K + k] = f2bf(in[i]);
  }
}

// W'_l[k][c] = sum_j ggnn_w[l][k][j] * w_ih[j][c]   (f32, [3][128][384])
__global__ void wprime_kernel(const float* __restrict__ ggnn_w, const float* __restrict__ w_ih,
                              float* __restrict__ wp) {
  int i = blockIdx.x * 256 + threadIdx.x;
  if (i >= 3 * 128 * 384) return;
  int l = i / (128 * 384), r = i % (128 * 384), k = r / 384, c = r % 384;
  const float* W = ggnn_w + l * 128 * 128;
  float s = 0.f;
  for (int j = 0; j < 128; ++j) s += W[k * 128 + j] * w_ih[j * 384 + c];
  wp[i] = s;
}

// Packed GRU weight, ALL 3 layers in one launch: b2p[l][ci][idx][e] u16.
// Zero quadrants excluded (ci<4: W' cols r|z|in; ci>=4: w_hh cols r|z|hn).
__global__ void build_b2p_kernel(const float* __restrict__ wp, const float* __restrict__ w_hh,
                                 u16* __restrict__ b2p) {
  int g = blockIdx.x * 256 + threadIdx.x;
  if (g >= 3 * 8 * 1536 * 8) return;
  int l = g / (8 * 1536 * 8);
  int rem = g % (8 * 1536 * 8);
  int e = rem & 7;
  int grp = rem >> 3;
  int ci = grp / 1536;
  int idx = grp % 1536;
  int n_lin = idx % 384;
  int ko = idx / 384;
  int k = ci * 32 + ko * 8 + e;
  float v = (k < 128) ? wp[l * 128 * 384 + k * 384 + n_lin] : w_hh[(k - 128) * 384 + n_lin];
  b2p[g] = f2bf(v);
}

// ---------------- node projection GEMM (f32 A -> bf16 frags) ----------------
__global__ __launch_bounds__(256)
void nodeproj_gemm(const float* __restrict__ A, const u16* __restrict__ BT,
                   const float* __restrict__ bias, u16* __restrict__ out, int M)
{
  constexpr int K_DIM = 64, N_DIM = 128, NT = 8, NCHUNK = 2;
  __shared__ u16 B_lds[N_DIM * 40];
  const int tid = threadIdx.x, lane = tid & 63, w = tid >> 6;
  const int strip = blockIdx.x * 64;
  const int ksub = (lane >> 4) * 8;
  union Frag { uint4 u; short8 s; };
  Frag af[NCHUNK];
  const int m_node = strip + w * 16 + (lane & 15);
  const bool avalid = (m_node < M);
#pragma unroll
  for (int ci = 0; ci < NCHUNK; ++ci) {
    int k0 = ci * 32 + ksub;
    short8 sv = {0,0,0,0,0,0,0,0};
    if (avalid) {
      const float* p = A + (size_t)m_node * K_DIM + k0;
      float4 f0 = *(const float4*)p;
      float4 f1 = *(const float4*)(p + 4);
      sv[0]=(short)f2bf(f0.x); sv[1]=(short)f2bf(f0.y); sv[2]=(short)f2bf(f0.z); sv[3]=(short)f2bf(f0.w);
      sv[4]=(short)f2bf(f1.x); sv[5]=(short)f2bf(f1.y); sv[6]=(short)f2bf(f1.z); sv[7]=(short)f2bf(f1.w);
    }
    af[ci].s = sv;
  }
  f32x4 acc[NT];
#pragma unroll
  for (int t = 0; t < NT; ++t) acc[t] = {0.f, 0.f, 0.f, 0.f};
  const int boff = (lane & 15) * 40 + ksub;
#pragma unroll
  for (int ci = 0; ci < NCHUNK; ++ci) {
    if (ci) __syncthreads();
    for (int g = tid; g < N_DIM * 4; g += 256) {
      int n = g >> 2, ko = g & 3;
      uint4 bv = *(const uint4*)(BT + (size_t)n * K_DIM + ci * 32 + ko * 8);
      *(uint4*)(&B_lds[n * 40 + ko * 8]) = bv;
    }
    __syncthreads();
    short8 a = af[ci].s;
#pragma unroll
    for (int t = 0; t < NT; ++t) {
      const short8 b = *(const short8*)(&B_lds[t * 16 * 40 + boff]);
      acc[t] = __builtin_amdgcn_mfma_f32_16x16x32_bf16(a, b, acc[t], 0, 0, 0);
    }
  }
  const int mrow = (lane >> 4) * 4;
#pragma unroll
  for (int t = 0; t < NT; ++t) {
    int col = t * 16 + (lane & 15);
    float bv = bias[col];
#pragma unroll
    for (int r = 0; r < 4; ++r) {
      int node = strip + w * 16 + mrow + r;
      if (node < M) out[(size_t)node * N_DIM + col] = f2bf(fmaxf(acc[t][r] + bv, 0.f));
    }
  }
}

// ---------------- GRU GEMM: barrier-free, LDS-free, 32x32/wave, 2-chunk software pipeline ----------------
// (measured 65 us @ MfmaUtil 11.5%; latency-bound — 9 structural variants (r4-r12) all land
//  65-135 with this the min. Round-13 fusion with agg regressed to 172 us. Keep.)
__global__ __launch_bounds__(256)
void gru_gemm(const u16* __restrict__ agg, const u16* __restrict__ h,
              const u16* __restrict__ b2p, const float* __restrict__ b_ih,
              const float* __restrict__ b_hh, u16* __restrict__ hout, int M)
{
  const int tid  = threadIdx.x;
  const int lane = tid & 63;
  const int qc   = tid >> 6;              // col-quarter 0..3 (32 cols each)
  const int strip = blockIdx.x * 32;      // one 32-row strip per block (100000 % 32 == 0)
  const int lrow  = lane & 15;
  const int quad  = lane >> 4;
  const int ksub  = quad * 8;
  if (strip >= M) return;

  f32x4 ar[2][2], az[2][2], ain[2][2], ahn[2][2];
#pragma unroll
  for (int s = 0; s < 2; ++s)
#pragma unroll
    for (int t = 0; t < 2; ++t) {
      ar[s][t] = {0.f,0.f,0.f,0.f}; az[s][t] = {0.f,0.f,0.f,0.f};
      ain[s][t] = {0.f,0.f,0.f,0.f}; ahn[s][t] = {0.f,0.f,0.f,0.f};
    }

  union Frag { uint4 u; short8 s8; };
  const int node0 = strip + lrow;
  const int node1 = strip + 16 + lrow;
  const u16* bb = b2p + ((size_t)quad * 384 + qc * 32 + lrow) * 8;

  Frag a0[2], a1[2], fbr[2][2], fbz[2][2], fbg[2][2];

  auto ldchunk = [&](int ci, int p) {
    const u16* ap = (ci < 4) ? (agg + ci * 32 + ksub) : (h + (ci - 4) * 32 + ksub);
    a0[p].u = *(const uint4*)(ap + (size_t)node0 * 128);
    a1[p].u = *(const uint4*)(ap + (size_t)node1 * 128);
    const u16* cb = bb + ci * 12288;
    fbr[p][0].u = *(const uint4*)(cb);
    fbr[p][1].u = *(const uint4*)(cb + 128);
    fbz[p][0].u = *(const uint4*)(cb + 1024);
    fbz[p][1].u = *(const uint4*)(cb + 1024 + 128);
    fbg[p][0].u = *(const uint4*)(cb + 2048);
    fbg[p][1].u = *(const uint4*)(cb + 2048 + 128);
  };

  ldchunk(0, 0);
#pragma unroll
  for (int ci = 0; ci < 8; ++ci) {
    const int p = ci & 1, q = p ^ 1;
    if (ci < 7) ldchunk(ci + 1, q);   // prefetch next chunk before consuming current
#pragma unroll
    for (int t = 0; t < 2; ++t) {
      ar[0][t] = __builtin_amdgcn_mfma_f32_16x16x32_bf16(a0[p].s8, fbr[p][t].s8, ar[0][t], 0, 0, 0);
      ar[1][t] = __builtin_amdgcn_mfma_f32_16x16x32_bf16(a1[p].s8, fbr[p][t].s8, ar[1][t], 0, 0, 0);
      az[0][t] = __builtin_amdgcn_mfma_f32_16x16x32_bf16(a0[p].s8, fbz[p][t].s8, az[0][t], 0, 0, 0);
      az[1][t] = __builtin_amdgcn_mfma_f32_16x16x32_bf16(a1[p].s8, fbz[p][t].s8, az[1][t], 0, 0, 0);
    }
    if (ci < 4) {
#pragma unroll
      for (int t = 0; t < 2; ++t) {
        ain[0][t] = __builtin_amdgcn_mfma_f32_16x16x32_bf16(a0[p].s8, fbg[p][t].s8, ain[0][t], 0, 0, 0);
        ain[1][t] = __builtin_amdgcn_mfma_f32_16x16x32_bf16(a1[p].s8, fbg[p][t].s8, ain[1][t], 0, 0, 0);
      }
    } else {
#pragma unroll
      for (int t = 0; t < 2; ++t) {
        ahn[0][t] = __builtin_amdgcn_mfma_f32_16x16x32_bf16(a0[p].s8, fbg[p][t].s8, ahn[0][t], 0, 0, 0);
        ahn[1][t] = __builtin_amdgcn_mfma_f32_16x16x32_bf16(a1[p].s8, fbg[p][t].s8, ahn[1][t], 0, 0, 0);
      }
    }
  }

  // GRU epilogue. D layout per tile: row = quad*4 + r, col = lrow.
#pragma unroll
  for (int t = 0; t < 2; ++t) {
    const int c = qc * 32 + t * 16 + lrow;
    const float brr = b_ih[c] + b_hh[c];
    const float bzz = b_ih[128 + c] + b_hh[128 + c];
    const float bin = b_ih[256 + c];
    const float bhn = b_hh[256 + c];
#pragma unroll
    for (int s = 0; s < 2; ++s) {
#pragma unroll
      for (int r = 0; r < 4; ++r) {
        const int nrow = strip + s * 16 + quad * 4 + r;
        float rg = sigmoid_f(ar[s][t][r] + brr);
        float zg = sigmoid_f(az[s][t][r] + bzz);
        float hv = ahn[s][t][r] + bhn;
        float ng = tanh_f(ain[s][t][r] + bin + rg * hv);
        float hp = bf2f(h[(size_t)nrow * 128 + c]);
        hout[(size_t)nrow * 128 + c] = f2bf((1.f - zg) * ng + zg * hp);
      }
    }
  }
}

// ---------------- CSR aggregation, row-vectorized (dense pass keeps gather L3-hot) ----------------
__global__ __launch_bounds__(256)
void agg_kernel(const u16* __restrict__ m, const int* __restrict__ ssrc,
                const int* __restrict__ offsets, u16* __restrict__ agg)
{
  int node = blockIdx.x * 4 + (threadIdx.x >> 6);
  int lane = threadIdx.x & 63;
  if (node >= N_NODES) return;
  const int g = lane >> 4, l = lane & 15;
  int beg = offsets[node], end = offsets[node + 1];
  float s[8] = {0.f,0.f,0.f,0.f,0.f,0.f,0.f,0.f};
  for (int e = beg; e < end; e += 8) {   // 2 groups of 4 edges in flight
    uint4 v0 = {0u,0u,0u,0u}, v1 = {0u,0u,0u,0u};
    int e0 = e + g, e1 = e + 4 + g;
    if (e0 < end) { int src = ssrc[e0]; v0 = *(const uint4*)(m + (size_t)src * 128 + l * 8); }
    if (e1 < end) { int src = ssrc[e1]; v1 = *(const uint4*)(m + (size_t)src * 128 + l * 8); }
    u32 w0[4] = {v0.x, v0.y, v0.z, v0.w};
    u32 w1[4] = {v1.x, v1.y, v1.z, v1.w};
#pragma unroll
    for (int i = 0; i < 4; ++i) {
      s[2*i]   += bf2f((u16)(w0[i] & 0xffffu)) + bf2f((u16)(w1[i] & 0xffffu));
      s[2*i+1] += bf2f((u16)(w0[i] >> 16))     + bf2f((u16)(w1[i] >> 16));
    }
  }
#pragma unroll
  for (int i = 0; i < 8; ++i) {
    s[i] += __shfl_xor(s[i], 16, 64);
    s[i] += __shfl_xor(s[i], 32, 64);
  }
  if (g == 0) {
    uint4 o;
    o.x = (u32)f2bf(s[0]) | ((u32)f2bf(s[1]) << 16);
    o.y = (u32)f2bf(s[2]) | ((u32)f2bf(s[3]) << 16);
    o.z = (u32)f2bf(s[4]) | ((u32)f2bf(s[5]) << 16);
    o.w = (u32)f2bf(s[6]) | ((u32)f2bf(s[7]) << 16);
    *(uint4*)(agg + (size_t)node * 128 + l * 8) = o;
  }
}

// ---------------- parallel segmented mean-pool (batch is sorted) ----------------
__global__ __launch_bounds__(256)
void pool_kernel(const u16* __restrict__ h, const int* __restrict__ batch,
                 const int* __restrict__ flags, float* __restrict__ sums)
{
  const int c = threadIdx.x & 127;
  const int half = threadIdx.x >> 7;
  const int base = blockIdx.x * 128;
  const int f = flags[1];
  int gcur = -1; float s = 0.f;
  for (int i = half; i < 128; i += 2) {
    int n = base + i;
    if (n >= N_NODES) break;
    int g = geti(batch, n, f);
    if (g != gcur) {
      if (gcur >= 0) atomicAdd(&sums[gcur * 128 + c], s);
      s = 0.f; gcur = g;
    }
    s += bf2f(h[(size_t)n * 128 + c]);
  }
  if (gcur >= 0) atomicAdd(&sums[gcur * 128 + c], s);
}

// ---------------- doc proj + LN + fusion + heads, f32 (one block per graph) ----------------
__global__ __launch_bounds__(256)
void head2_kernel(const float* __restrict__ sums, const int* __restrict__ batch,
                  const int* __restrict__ flags,
                  const float* __restrict__ doc, const float* __restrict__ doc_w, const float* __restrict__ doc_b,
                  const float* __restrict__ ln_g, const float* __restrict__ ln_b,
                  const float* __restrict__ fus_w, const float* __restrict__ fus_b,
                  const float* __restrict__ task_w, const float* __restrict__ task_b,
                  const float* __restrict__ time_w, const float* __restrict__ time_b,
                  float* __restrict__ out_task, float* __restrict__ out_time)
{
  const int g = blockIdx.x;
  const int t = threadIdx.x;
  __shared__ float fusion[256];
  __shared__ float fh[128];
  __shared__ float dpart[256];
  __shared__ int seg[2];

  if (t < 2) {
    int f = flags[1];
    int target = g + t, lo = 0, hi = N_NODES;
    while (lo < hi) { int mid = (lo + hi) >> 1; if (geti(batch, mid, f) < target) lo = mid + 1; else hi = mid; }
    seg[t] = lo;
  }
  {
    int c = t & 127, kh = t >> 7;
    float s = 0.f;
    for (int k = kh * 384; k < kh * 384 + 384; ++k) s += doc[g * 768 + k] * doc_w[k * 128 + c];
    dpart[t] = s;
  }
  __syncthreads();

  if (t < 128) {
    float cnt = (float)(seg[1] - seg[0]);
    fusion[t] = sums[g * 128 + t] / fmaxf(cnt, 1.f);
  } else {
    int c = t - 128;
    fusion[t] = fmaxf(dpart[c] + dpart[c + 128] + doc_b[c], 0.f);
  }
  __syncthreads();

  float mu = 0.f;
  for (int i = 0; i < 256; ++i) mu += fusion[i];
  mu *= (1.f / 256.f);
  float var = 0.f;
  for (int i = 0; i < 256; ++i) { float d = fusion[i] - mu; var += d * d; }
  var *= (1.f / 256.f);
  float inv = rsqrtf(var + 1e-5f);
  float norm = (fusion[t] - mu) * inv * ln_g[t] + ln_b[t];
  __syncthreads();
  fusion[t] = norm;
  __syncthreads();

  if (t < 128) {
    float s = 0.f;
    for (int k = 0; k < 256; ++k) s += fusion[k] * fus_w[k * 128 + t];
    s += fus_b[t];
    fh[t] = fmaxf(s, 0.f);
  }
  __syncthreads();

  if (t < 32) {
    float s = 0.f;
    for (int k = 0; k < 128; ++k) s += fh[k] * task_w[k * 32 + t];
    s += task_b[t];
    out_task[g * 32 + t] = s;
  }
  if (t == 32) {
    float s = 0.f;
    for (int k = 0; k < 128; ++k) s += fh[k] * time_w[k];
    s += time_b[0];
    out_time[g] = s;
  }
}

// ---------------- launch ----------------
extern "C" void kernel_launch(void* const* d_in, const int* in_sizes, int n_in,
                              void* d_out, int out_size, void* d_ws, size_t ws_size,
                              hipStream_t stream)
{
  const float* x        = (const float*)d_in[0];
  const float* doc      = (const float*)d_in[1];
  const int*   ei       = (const int*)d_in[2];
  const int*   batch    = (const int*)d_in[3];
  const float* node_w   = (const float*)d_in[4];
  const float* node_b   = (const float*)d_in[5];
  const float* ggnn_w   = (const float*)d_in[6];
  const float* gru_w_ih = (const float*)d_in[7];
  const float* gru_b_ih = (const float*)d_in[8];
  const float* gru_w_hh = (const float*)d_in[9];
  const float* gru_b_hh = (const float*)d_in[10];
  const float* doc_w    = (const float*)d_in[11];
  const float* doc_b    = (const float*)d_in[12];
  const float* ln_g     = (const float*)d_in[13];
  const float* ln_b     = (const float*)d_in[14];
  const float* fus_w    = (const float*)d_in[15];
  const float* fus_b    = (const float*)d_in[16];
  const float* task_w   = (const float*)d_in[17];
  const float* task_b   = (const float*)d_in[18];
  const float* time_w   = (const float*)d_in[19];
  const float* time_b   = (const float*)d_in[20];

  char* ws = (char*)d_ws;
  size_t off = 0;
  auto alloc = [&](size_t bytes) -> void* {
    void* p = ws + off;
    off = (off + bytes + 255) & ~(size_t)255;
    return p;
  };
  u16* aggb   = (u16*)alloc((size_t)N_NODES * 128 * 2);
  u16* hA     = (u16*)alloc((size_t)N_NODES * 128 * 2);
  u16* hB     = (u16*)alloc((size_t)N_NODES * 128 * 2);
  u16* nwT    = (u16*)alloc(64 * 128 * 2);
  u16* b2p    = (u16*)alloc(3 * 8 * 1536 * 8 * 2);
  float* wp   = (float*)alloc(3 * 128 * 384 * 4);
  float* sums = (float*)alloc(N_GRAPHS * 128 * 4);
  int* counts = (int*)alloc((size_t)N_NODES * 4);
  int* offs   = (int*)alloc((size_t)(N_NODES + 1) * 4);
  int* ssrc   = (int*)alloc((size_t)N_EDGES * 4);
  u16* rankb  = (u16*)alloc((size_t)N_EDGES * 2);
  int* bsum   = (int*)alloc(SCAN_BLOCKS * 4);
  int* bbase  = (int*)alloc(SCAN_BLOCKS * 4);
  int* flags  = (int*)alloc(2 * 4);

  hipMemsetAsync(counts, 0, (size_t)N_NODES * 4, stream);
  hipMemsetAsync(sums, 0, (size_t)N_GRAPHS * 128 * 4, stream);

  detect_i64_kernel<<<1, 64, 0, stream>>>(ei, batch, flags);
  hist_kernel<<<(N_EDGES + 255) / 256, 256, 0, stream>>>(ei, flags, counts, rankb);
  scanA_kernel<<<SCAN_BLOCKS, 1024, 0, stream>>>(counts, bsum);
  scanB_kernel<<<1, 64, 0, stream>>>(bsum, bbase, offs);
  scanC_kernel<<<SCAN_BLOCKS, 1024, 0, stream>>>(counts, bbase, offs);
  scatter_kernel<<<(N_EDGES + 255) / 256, 256, 0, stream>>>(ei, flags, offs, rankb, ssrc);

  transpose_kernel<<<(64 * 128 + 255) / 256, 256, 0, stream>>>(node_w, nwT, 64, 128);
  wprime_kernel<<<(3 * 128 * 384 + 255) / 256, 256, 0, stream>>>(ggnn_w, gru_w_ih, wp);
  build_b2p_kernel<<<(3 * 8 * 1536 * 8 + 255) / 256, 256, 0, stream>>>(wp, gru_w_hh, b2p);

  const int GB = (N_NODES + 63) / 64;    // 1563
  const int GB32 = N_NODES / 32;         // 3125
  nodeproj_gemm<<<GB, 256, 0, stream>>>(x, nwT, node_b, hA, N_NODES);

  u16* hcur = hA;
  u16* hnext = hB;
  for (int l = 0; l < 3; ++l) {
    agg_kernel<<<(N_NODES + 3) / 4, 256, 0, stream>>>(hcur, ssrc, offs, aggb);
    gru_gemm<<<GB32, 256, 0, stream>>>(aggb, hcur, b2p + (size_t)l * 8 * 1536 * 8,
                                       gru_b_ih, gru_b_hh, hnext, N_NODES);
    u16* tmp = hcur; hcur = hnext; hnext = tmp;
  }

  pool_kernel<<<(N_NODES + 127) / 128, 256, 0, stream>>>(hcur, batch, flags, sums);

  float* out_task = (float*)d_out;
  float* out_time = out_task + N_GRAPHS * 32;
  head2_kernel<<<N_GRAPHS, 256, 0, stream>>>(sums, batch, flags, doc, doc_w, doc_b, ln_g, ln_b,
                                             fus_w, fus_b, task_w, task_b, time_w, time_b,
                                             out_task, out_time);
}